// Round 1
// baseline (709.603 us; speedup 1.0000x reference)
//
#include <hip/hip_runtime.h>

typedef __attribute__((ext_vector_type(8))) __bf16 bf16x8;
typedef __attribute__((ext_vector_type(4))) float f32x4;

#define NEG_BIG (-1e30f)

__device__ __forceinline__ unsigned short f2b(float f) {
    unsigned int u = __float_as_uint(f);
    u += 0x7FFFu + ((u >> 16) & 1u);
    return (unsigned short)(u >> 16);
}
__device__ __forceinline__ float b2f(unsigned short h) {
    return __uint_as_float(((unsigned int)h) << 16);
}

// ---------------- elementwise f32 -> (hi, lo) bf16 split ----------------
__global__ __launch_bounds__(256) void k_convert_split(
    const float* __restrict__ x, unsigned short* __restrict__ hi,
    unsigned short* __restrict__ lo, int n4)
{
    int i = blockIdx.x * 256 + threadIdx.x;
    if (i >= n4) return;
    float4 v = reinterpret_cast<const float4*>(x)[i];
    ushort4 h, l;
    h.x = f2b(v.x); l.x = f2b(v.x - b2f(h.x));
    h.y = f2b(v.y); l.y = f2b(v.y - b2f(h.y));
    h.z = f2b(v.z); l.z = f2b(v.z - b2f(h.z));
    h.w = f2b(v.w); l.w = f2b(v.w - b2f(h.w));
    reinterpret_cast<ushort4*>(hi)[i] = h;
    reinterpret_cast<ushort4*>(lo)[i] = l;
}

// ------------- W (K x N, f32) -> Wt (N x K) hi/lo bf16 -------------
__global__ __launch_bounds__(256) void k_transpose_split(
    const float* __restrict__ W, unsigned short* __restrict__ Th,
    unsigned short* __restrict__ Tl, int K, int N)
{
    __shared__ float tile[64][65];
    const int n0 = blockIdx.x * 64, k0 = blockIdx.y * 64;
    const int c = threadIdx.x & 63, r0 = threadIdx.x >> 6;
    for (int rr = r0; rr < 64; rr += 4)
        tile[rr][c] = W[(size_t)(k0 + rr) * N + n0 + c];
    __syncthreads();
    for (int rr = r0; rr < 64; rr += 4) {
        float v = tile[c][rr];
        unsigned short h = f2b(v);
        size_t idx = (size_t)(n0 + rr) * K + k0 + c;
        Th[idx] = h;
        Tl[idx] = f2b(v - b2f(h));
    }
}

// ------------- split-bf16 GEMM: C = A * B^T(stored [N][K]) -------------
// A: M x K as (Ah + Al), B: N x K as (Bh + Bl). acc = ah*bh + ah*bl + al*bh.
// 128x128 tile, BK=32, 4 waves (2x2), each wave 64x64 = 4x4 16x16x32 frags.
__global__ __launch_bounds__(256) void k_gemm_split(
    const unsigned short* __restrict__ Ah, const unsigned short* __restrict__ Al,
    const unsigned short* __restrict__ Bh, const unsigned short* __restrict__ Bl,
    void* __restrict__ Cout, const float* __restrict__ bias,
    int M, int N, int K, int outF32)
{
    __shared__ __align__(16) unsigned short Ahs[128][32];
    __shared__ __align__(16) unsigned short Als[128][32];
    __shared__ __align__(16) unsigned short Bhs[128][32];
    __shared__ __align__(16) unsigned short Bls[128][32];

    const int tid  = threadIdx.x;
    const int lane = tid & 63, wid = tid >> 6;
    const int wr = wid >> 1, wc = wid & 1;
    const int lrow = lane & 15, lko = (lane >> 4) << 3;
    const int trow = tid >> 2, tk = (tid & 3) << 3;
    const int bm = blockIdx.y, bn = blockIdx.x;

    f32x4 acc[4][4] = {};

    const size_t aoff = (size_t)(bm * 128 + trow) * K + tk;
    const size_t boff = (size_t)(bn * 128 + trow) * K + tk;
    const size_t half = (size_t)64 * K;

    for (int k0 = 0; k0 < K; k0 += 32) {
        *reinterpret_cast<uint4*>(&Ahs[trow][tk])      = *reinterpret_cast<const uint4*>(&Ah[aoff + k0]);
        *reinterpret_cast<uint4*>(&Ahs[trow + 64][tk]) = *reinterpret_cast<const uint4*>(&Ah[aoff + half + k0]);
        *reinterpret_cast<uint4*>(&Als[trow][tk])      = *reinterpret_cast<const uint4*>(&Al[aoff + k0]);
        *reinterpret_cast<uint4*>(&Als[trow + 64][tk]) = *reinterpret_cast<const uint4*>(&Al[aoff + half + k0]);
        *reinterpret_cast<uint4*>(&Bhs[trow][tk])      = *reinterpret_cast<const uint4*>(&Bh[boff + k0]);
        *reinterpret_cast<uint4*>(&Bhs[trow + 64][tk]) = *reinterpret_cast<const uint4*>(&Bh[boff + half + k0]);
        *reinterpret_cast<uint4*>(&Bls[trow][tk])      = *reinterpret_cast<const uint4*>(&Bl[boff + k0]);
        *reinterpret_cast<uint4*>(&Bls[trow + 64][tk]) = *reinterpret_cast<const uint4*>(&Bl[boff + half + k0]);
        __syncthreads();

        bf16x8 ahf[4], alf[4], bhf[4], blf[4];
        #pragma unroll
        for (int m = 0; m < 4; ++m) {
            ahf[m] = *reinterpret_cast<const bf16x8*>(&Ahs[wr * 64 + m * 16 + lrow][lko]);
            alf[m] = *reinterpret_cast<const bf16x8*>(&Als[wr * 64 + m * 16 + lrow][lko]);
        }
        #pragma unroll
        for (int n = 0; n < 4; ++n) {
            bhf[n] = *reinterpret_cast<const bf16x8*>(&Bhs[wc * 64 + n * 16 + lrow][lko]);
            blf[n] = *reinterpret_cast<const bf16x8*>(&Bls[wc * 64 + n * 16 + lrow][lko]);
        }
        #pragma unroll
        for (int m = 0; m < 4; ++m)
            #pragma unroll
            for (int n = 0; n < 4; ++n) {
                acc[m][n] = __builtin_amdgcn_mfma_f32_16x16x32_bf16(ahf[m], bhf[n], acc[m][n], 0, 0, 0);
                acc[m][n] = __builtin_amdgcn_mfma_f32_16x16x32_bf16(ahf[m], blf[n], acc[m][n], 0, 0, 0);
                acc[m][n] = __builtin_amdgcn_mfma_f32_16x16x32_bf16(alf[m], bhf[n], acc[m][n], 0, 0, 0);
            }
        __syncthreads();
    }

    const int rbase = bm * 128 + wr * 64 + ((lane >> 4) << 2);
    const int cbase = bn * 128 + wc * 64 + lrow;
    #pragma unroll
    for (int m = 0; m < 4; ++m)
        #pragma unroll
        for (int n = 0; n < 4; ++n) {
            const int col = cbase + n * 16;
            const float bv = bias ? bias[col] : 0.0f;
            #pragma unroll
            for (int r = 0; r < 4; ++r) {
                const size_t idx = (size_t)(rbase + m * 16 + r) * N + col;
                const float v = acc[m][n][r] + bv;
                if (outF32) ((float*)Cout)[idx] = v;
                else        ((unsigned short*)Cout)[idx] = f2b(v);
            }
        }
}

// ------------- fused causal GQA attention with ALiBi -------------
// block = (b, g, 16-row q tile); 4 waves = 4 q-heads (r = 0..3) sharing kv head g.
__global__ __launch_bounds__(256) void k_attn(
    const unsigned short* __restrict__ Qb,   // (B*T) x 2048 bf16
    const unsigned short* __restrict__ KVb,  // (B*T) x 1024 bf16 (k | v)
    unsigned short* __restrict__ AOh,        // (B*T) x 2048 bf16 hi
    unsigned short* __restrict__ AOl)        // (B*T) x 2048 bf16 lo
{
    __shared__ __align__(16) unsigned short Ksl[32][128];
    __shared__ __align__(16) unsigned short Vtl[128][32];
    __shared__ __align__(16) unsigned short Psl[4][16][32];

    const int blk = blockIdx.x;
    const int qt = blk & 127;
    const int g  = (blk >> 7) & 3;
    const int b  = blk >> 9;
    const int q0 = qt * 16;
    const int tid = threadIdx.x;
    const int lane = tid & 63;
    const int w = tid >> 6;          // rep index r
    const int h = w * 4 + g;         // query head = r*KVH + g
    const float slope = exp2f(-0.5f * (float)(h + 1));
    const float isq = 0.088388347648318447f; // 1/sqrt(128)
    const int lrow = lane & 15;
    const int lko  = (lane >> 4) << 3;
    const int rowg = (lane >> 4) << 2;

    bf16x8 qf[4];
    {
        const size_t qoff = (size_t)(b * 2048 + q0 + lrow) * 2048 + h * 128 + lko;
        #pragma unroll
        for (int kk = 0; kk < 4; ++kk)
            qf[kk] = *reinterpret_cast<const bf16x8*>(&Qb[qoff + kk * 32]);
    }

    f32x4 oacc[8] = {};
    float mrow[4] = {NEG_BIG, NEG_BIG, NEG_BIG, NEG_BIG};
    float lsum[4] = {0.f, 0.f, 0.f, 0.f};

    const int nkb = (q0 + 16 + 31) >> 5;
    const int skey = tid >> 4;
    const int sd0  = (tid & 15) << 3;

    for (int kb = 0; kb < nkb; ++kb) {
        const int j0 = kb << 5;
        __syncthreads();  // prior-iter LDS reads done
        #pragma unroll
        for (int p = 0; p < 2; ++p) {
            const int key = skey + p * 16;
            const size_t off = (size_t)(b * 2048 + j0 + key) * 1024 + g * 128 + sd0;
            *reinterpret_cast<uint4*>(&Ksl[key][sd0]) = *reinterpret_cast<const uint4*>(&KVb[off]);
            unsigned short vv[8];
            *reinterpret_cast<uint4*>(vv) = *reinterpret_cast<const uint4*>(&KVb[off + 512]);
            #pragma unroll
            for (int i = 0; i < 8; ++i) Vtl[sd0 + i][key] = vv[i];
        }
        __syncthreads();

        // S = Q K^T for 16 q-rows x 32 keys
        f32x4 sa[2] = {};
        #pragma unroll
        for (int c = 0; c < 2; ++c)
            #pragma unroll
            for (int kk = 0; kk < 4; ++kk) {
                bf16x8 kf = *reinterpret_cast<const bf16x8*>(&Ksl[c * 16 + lrow][kk * 32 + lko]);
                sa[c] = __builtin_amdgcn_mfma_f32_16x16x32_bf16(qf[kk], kf, sa[c], 0, 0, 0);
            }

        float pvv[2][4], alpha[4];
        #pragma unroll
        for (int r = 0; r < 4; ++r) {
            const int irow = q0 + rowg + r;
            float best = NEG_BIG;
            #pragma unroll
            for (int c = 0; c < 2; ++c) {
                const int j = j0 + c * 16 + lrow;
                float v = (j <= irow) ? (sa[c][r] * isq + slope * (float)(j - irow)) : NEG_BIG;
                pvv[c][r] = v;
                best = fmaxf(best, v);
            }
            best = fmaxf(best, __shfl_xor(best, 1));
            best = fmaxf(best, __shfl_xor(best, 2));
            best = fmaxf(best, __shfl_xor(best, 4));
            best = fmaxf(best, __shfl_xor(best, 8));
            const float mn = fmaxf(mrow[r], best);
            alpha[r] = __expf(mrow[r] - mn);
            mrow[r] = mn;
            float s = 0.f;
            #pragma unroll
            for (int c = 0; c < 2; ++c) {
                const float p = __expf(pvv[c][r] - mn);
                pvv[c][r] = p;
                s += p;
            }
            s += __shfl_xor(s, 1);
            s += __shfl_xor(s, 2);
            s += __shfl_xor(s, 4);
            s += __shfl_xor(s, 8);
            lsum[r] = lsum[r] * alpha[r] + s;
        }

        #pragma unroll
        for (int f = 0; f < 8; ++f)
            #pragma unroll
            for (int r = 0; r < 4; ++r)
                oacc[f][r] *= alpha[r];

        // P -> LDS (bf16) for PV MFMA A-operand
        #pragma unroll
        for (int c = 0; c < 2; ++c)
            #pragma unroll
            for (int r = 0; r < 4; ++r)
                Psl[w][rowg + r][c * 16 + lrow] = f2b(pvv[c][r]);
        __syncthreads();  // cheap & safe ordering for P round-trip

        bf16x8 pf = *reinterpret_cast<const bf16x8*>(&Psl[w][lrow][lko]);
        #pragma unroll
        for (int nb = 0; nb < 8; ++nb) {
            bf16x8 vf = *reinterpret_cast<const bf16x8*>(&Vtl[nb * 16 + lrow][lko]);
            oacc[nb] = __builtin_amdgcn_mfma_f32_16x16x32_bf16(pf, vf, oacc[nb], 0, 0, 0);
        }
    }

    #pragma unroll
    for (int nb = 0; nb < 8; ++nb)
        #pragma unroll
        for (int r = 0; r < 4; ++r) {
            const int row = q0 + rowg + r;
            const int col = h * 128 + nb * 16 + lrow;
            const float v = oacc[nb][r] / lsum[r];
            const size_t idx = (size_t)(b * 2048 + row) * 2048 + col;
            unsigned short hh = f2b(v);
            AOh[idx] = hh;
            AOl[idx] = f2b(v - b2f(hh));
        }
}

extern "C" void kernel_launch(void* const* d_in, const int* in_sizes, int n_in,
                              void* d_out, int out_size, void* d_ws, size_t ws_size,
                              hipStream_t stream)
{
    const float* x   = (const float*)d_in[0];  // (2,2048,2048)
    const float* Wq  = (const float*)d_in[1];  // (2048,2048)
    const float* Wkv = (const float*)d_in[2];  // (2048,1024)
    const float* Wo  = (const float*)d_in[3];  // (2048,2048)
    const float* bo  = (const float*)d_in[4];  // (2048,)

    char* ws = (char*)d_ws;
    unsigned short* xhi = (unsigned short*)(ws + (size_t)0);          // 16MB (later AO hi)
    unsigned short* xlo = (unsigned short*)(ws + ((size_t)16 << 20)); // 16MB (later AO lo)
    unsigned short* Wth = (unsigned short*)(ws + ((size_t)32 << 20)); // 8MB
    unsigned short* Wtl = (unsigned short*)(ws + ((size_t)40 << 20)); // 8MB
    unsigned short* Qb  = (unsigned short*)(ws + ((size_t)48 << 20)); // 16MB
    unsigned short* KVb = (unsigned short*)(ws + ((size_t)64 << 20)); // 8MB
    // total 72MB

    // x -> hi/lo bf16
    k_convert_split<<<8192, 256, 0, stream>>>(x, xhi, xlo, (2 * 2048 * 2048) / 4);

    // Q = x @ Wq           (4096 x 2048 x 2048)
    k_transpose_split<<<dim3(32, 32), 256, 0, stream>>>(Wq, Wth, Wtl, 2048, 2048);
    k_gemm_split<<<dim3(16, 32), 256, 0, stream>>>(xhi, xlo, Wth, Wtl, Qb, nullptr,
                                                   4096, 2048, 2048, 0);
    // KV = x @ Wkv         (4096 x 1024 x 2048)
    k_transpose_split<<<dim3(16, 32), 256, 0, stream>>>(Wkv, Wth, Wtl, 2048, 1024);
    k_gemm_split<<<dim3(8, 32), 256, 0, stream>>>(xhi, xlo, Wth, Wtl, KVb, nullptr,
                                                  4096, 1024, 2048, 0);
    // attention -> AO (reuses x buffers)
    k_attn<<<1024, 256, 0, stream>>>(Qb, KVb, xhi, xlo);

    // out = AO @ Wo + bo   (4096 x 2048 x 2048), f32 out
    k_transpose_split<<<dim3(32, 32), 256, 0, stream>>>(Wo, Wth, Wtl, 2048, 2048);
    k_gemm_split<<<dim3(16, 32), 256, 0, stream>>>(xhi, xlo, Wth, Wtl, d_out, bo,
                                                   4096, 2048, 2048, 1);
}

// Round 2
// 522.121 us; speedup vs baseline: 1.3591x; 1.3591x over previous
//
#include <hip/hip_runtime.h>

typedef __attribute__((ext_vector_type(8))) __bf16 bf16x8;
typedef __attribute__((ext_vector_type(4))) float f32x4;

#define NEG_BIG (-1e30f)

__device__ __forceinline__ unsigned short f2b(float f) {
    unsigned int u = __float_as_uint(f);
    u += 0x7FFFu + ((u >> 16) & 1u);
    return (unsigned short)(u >> 16);
}
__device__ __forceinline__ float b2f(unsigned short h) {
    return __uint_as_float(((unsigned int)h) << 16);
}

typedef const __attribute__((address_space(1))) unsigned int* gas_ptr;
typedef __attribute__((address_space(3))) unsigned int* las_ptr;
__device__ __forceinline__ void gload16(const void* g, void* l) {
    __builtin_amdgcn_global_load_lds((gas_ptr)g, (las_ptr)l, 16, 0, 0);
}

// ---------------- elementwise f32 -> (hi, lo) bf16 split ----------------
__global__ __launch_bounds__(256) void k_convert_split(
    const float* __restrict__ x, unsigned short* __restrict__ hi,
    unsigned short* __restrict__ lo, int n4)
{
    int i = blockIdx.x * 256 + threadIdx.x;
    if (i >= n4) return;
    float4 v = reinterpret_cast<const float4*>(x)[i];
    ushort4 h, l;
    h.x = f2b(v.x); l.x = f2b(v.x - b2f(h.x));
    h.y = f2b(v.y); l.y = f2b(v.y - b2f(h.y));
    h.z = f2b(v.z); l.z = f2b(v.z - b2f(h.z));
    h.w = f2b(v.w); l.w = f2b(v.w - b2f(h.w));
    reinterpret_cast<ushort4*>(hi)[i] = h;
    reinterpret_cast<ushort4*>(lo)[i] = l;
}

// ------------- W (K x N, f32) -> Wt (N x K) hi/lo bf16 -------------
__global__ __launch_bounds__(256) void k_transpose_split(
    const float* __restrict__ W, unsigned short* __restrict__ Th,
    unsigned short* __restrict__ Tl, int K, int N)
{
    __shared__ float tile[64][65];
    const int n0 = blockIdx.x * 64, k0 = blockIdx.y * 64;
    const int c = threadIdx.x & 63, r0 = threadIdx.x >> 6;
    for (int rr = r0; rr < 64; rr += 4)
        tile[rr][c] = W[(size_t)(k0 + rr) * N + n0 + c];
    __syncthreads();
    for (int rr = r0; rr < 64; rr += 4) {
        float v = tile[c][rr];
        unsigned short h = f2b(v);
        size_t idx = (size_t)(n0 + rr) * K + k0 + c;
        Th[idx] = h;
        Tl[idx] = f2b(v - b2f(h));
    }
}

// ------------- split-bf16 GEMM: C = A * B^T(stored [N][K]) -------------
__global__ __launch_bounds__(256) void k_gemm_split(
    const unsigned short* __restrict__ Ah, const unsigned short* __restrict__ Al,
    const unsigned short* __restrict__ Bh, const unsigned short* __restrict__ Bl,
    void* __restrict__ Cout, const float* __restrict__ bias,
    int M, int N, int K, int outF32)
{
    __shared__ __align__(16) unsigned short Ahs[128][32];
    __shared__ __align__(16) unsigned short Als[128][32];
    __shared__ __align__(16) unsigned short Bhs[128][32];
    __shared__ __align__(16) unsigned short Bls[128][32];

    const int tid  = threadIdx.x;
    const int lane = tid & 63, wid = tid >> 6;
    const int wr = wid >> 1, wc = wid & 1;
    const int lrow = lane & 15, lko = (lane >> 4) << 3;
    const int trow = tid >> 2, tk = (tid & 3) << 3;
    const int bm = blockIdx.y, bn = blockIdx.x;
    const int wbyte = wid * 1024;   // lane-linear: thread t -> byte 16*t

    f32x4 acc[4][4] = {};

    const size_t aoff = (size_t)(bm * 128 + trow) * K + tk;
    const size_t boff = (size_t)(bn * 128 + trow) * K + tk;
    const size_t half = (size_t)64 * K;

    for (int k0 = 0; k0 < K; k0 += 32) {
        gload16(&Ah[aoff + k0],        (char*)&Ahs[0][0] + wbyte);
        gload16(&Ah[aoff + half + k0], (char*)&Ahs[0][0] + 4096 + wbyte);
        gload16(&Al[aoff + k0],        (char*)&Als[0][0] + wbyte);
        gload16(&Al[aoff + half + k0], (char*)&Als[0][0] + 4096 + wbyte);
        gload16(&Bh[boff + k0],        (char*)&Bhs[0][0] + wbyte);
        gload16(&Bh[boff + half + k0], (char*)&Bhs[0][0] + 4096 + wbyte);
        gload16(&Bl[boff + k0],        (char*)&Bls[0][0] + wbyte);
        gload16(&Bl[boff + half + k0], (char*)&Bls[0][0] + 4096 + wbyte);
        __syncthreads();

        bf16x8 ahf[4], alf[4], bhf[4], blf[4];
        #pragma unroll
        for (int m = 0; m < 4; ++m) {
            ahf[m] = *reinterpret_cast<const bf16x8*>(&Ahs[wr * 64 + m * 16 + lrow][lko]);
            alf[m] = *reinterpret_cast<const bf16x8*>(&Als[wr * 64 + m * 16 + lrow][lko]);
        }
        #pragma unroll
        for (int n = 0; n < 4; ++n) {
            bhf[n] = *reinterpret_cast<const bf16x8*>(&Bhs[wc * 64 + n * 16 + lrow][lko]);
            blf[n] = *reinterpret_cast<const bf16x8*>(&Bls[wc * 64 + n * 16 + lrow][lko]);
        }
        #pragma unroll
        for (int m = 0; m < 4; ++m)
            #pragma unroll
            for (int n = 0; n < 4; ++n) {
                acc[m][n] = __builtin_amdgcn_mfma_f32_16x16x32_bf16(ahf[m], bhf[n], acc[m][n], 0, 0, 0);
                acc[m][n] = __builtin_amdgcn_mfma_f32_16x16x32_bf16(ahf[m], blf[n], acc[m][n], 0, 0, 0);
                acc[m][n] = __builtin_amdgcn_mfma_f32_16x16x32_bf16(alf[m], bhf[n], acc[m][n], 0, 0, 0);
            }
        __syncthreads();
    }

    const int rbase = bm * 128 + wr * 64 + ((lane >> 4) << 2);
    const int cbase = bn * 128 + wc * 64 + lrow;
    #pragma unroll
    for (int m = 0; m < 4; ++m)
        #pragma unroll
        for (int n = 0; n < 4; ++n) {
            const int col = cbase + n * 16;
            const float bv = bias ? bias[col] : 0.0f;
            #pragma unroll
            for (int r = 0; r < 4; ++r) {
                const size_t idx = (size_t)(rbase + m * 16 + r) * N + col;
                const float v = acc[m][n][r] + bv;
                if (outF32) ((float*)Cout)[idx] = v;
                else        ((unsigned short*)Cout)[idx] = f2b(v);
            }
        }
}

// ------------- fused causal GQA attention with ALiBi -------------
// block = (b, g, 16-row q tile); 4 waves = 4 q-heads sharing kv head g.
// K LDS XOR-swizzled; V gather-transposed into padded [128][40]; P per-wave.
__global__ __launch_bounds__(256) void k_attn(
    const unsigned short* __restrict__ Qb,   // (B*T) x 2048 bf16
    const unsigned short* __restrict__ KVb,  // (B*T) x 1024 bf16 (k | v)
    unsigned short* __restrict__ AOh,        // (B*T) x 2048 bf16 hi
    unsigned short* __restrict__ AOl)        // (B*T) x 2048 bf16 lo
{
    __shared__ __align__(16) unsigned short Ksl[32][128];  // [key][dim ^ ((key&7)<<3)]
    __shared__ __align__(16) unsigned short Vt[128][40];   // [dim][key], padded
    __shared__ __align__(16) unsigned short Psl[4][16][40];

    // complementary-qt pairing: blocks {v=0..3} on the same CU get qt and 127-qt
    const int blk = blockIdx.x;
    const int u = blk & 255, v = blk >> 8;
    const int g = v;
    const int b = u >> 7;
    const int q7 = u & 127;
    const int qt = (v & 1) ? (127 - q7) : q7;
    const int q0 = qt * 16;

    const int tid = threadIdx.x;
    const int lane = tid & 63;
    const int w = tid >> 6;          // rep index r
    const int h = w * 4 + g;         // query head
    const float slope = exp2f(-0.5f * (float)(h + 1));
    const float isq = 0.088388347648318447f; // 1/sqrt(128)
    const int lrow = lane & 15;
    const int lko  = (lane >> 4) << 3;
    const int rowg = (lane >> 4) << 2;

    bf16x8 qf[4];
    {
        const size_t qoff = (size_t)(b * 2048 + q0 + lrow) * 2048 + h * 128 + lko;
        #pragma unroll
        for (int kk = 0; kk < 4; ++kk)
            qf[kk] = *reinterpret_cast<const bf16x8*>(&Qb[qoff + kk * 32]);
    }

    f32x4 oacc[8] = {};
    float mrow[4] = {NEG_BIG, NEG_BIG, NEG_BIG, NEG_BIG};
    float lsum[4] = {0.f, 0.f, 0.f, 0.f};

    const int nkb = (q0 + 16 + 31) >> 5;
    const int skey = tid >> 4;                 // 0..15
    const int sd0  = (tid & 15) << 3;          // 0..120
    const int vdim = tid & 127;                // V gather: dim
    const int vkg  = tid >> 7;                 // V gather: key-group parity

    for (int kb = 0; kb < nkb; ++kb) {
        const int j0 = kb << 5;
        __syncthreads();  // prior-iter LDS reads done

        // K: async global->LDS, swizzle via pre-permuted global src (linear LDS dest)
        #pragma unroll
        for (int p = 0; p < 2; ++p) {
            const int key = skey + p * 16;
            const int d0s = sd0 ^ ((key & 7) << 3);
            const size_t off = (size_t)(b * 2048 + j0 + key) * 1024 + g * 128 + d0s;
            gload16(&KVb[off], (char*)&Ksl[0][0] + p * 4096 + w * 1024);
        }
        // V: gather-transpose (coalesced 2B lane reads), conflict-free b128 writes
        #pragma unroll
        for (int kgi = vkg; kgi < 4; kgi += 2) {
            unsigned short vv[8];
            #pragma unroll
            for (int j = 0; j < 8; ++j)
                vv[j] = KVb[(size_t)(b * 2048 + j0 + kgi * 8 + j) * 1024 + 512 + g * 128 + vdim];
            *reinterpret_cast<uint4*>(&Vt[vdim][kgi * 8]) = *reinterpret_cast<const uint4*>(vv);
        }
        __syncthreads();

        // S = Q K^T for 16 q-rows x 32 keys
        f32x4 sa[2] = {};
        #pragma unroll
        for (int c = 0; c < 2; ++c) {
            const int krow = c * 16 + lrow;
            #pragma unroll
            for (int kk = 0; kk < 4; ++kk) {
                bf16x8 kf = *reinterpret_cast<const bf16x8*>(
                    &Ksl[krow][(kk * 32 + lko) ^ ((krow & 7) << 3)]);
                sa[c] = __builtin_amdgcn_mfma_f32_16x16x32_bf16(qf[kk], kf, sa[c], 0, 0, 0);
            }
        }

        float pvv[2][4], alpha[4];
        #pragma unroll
        for (int r = 0; r < 4; ++r) {
            const int irow = q0 + rowg + r;
            float best = NEG_BIG;
            #pragma unroll
            for (int c = 0; c < 2; ++c) {
                const int j = j0 + c * 16 + lrow;
                float vsc = (j <= irow) ? (sa[c][r] * isq + slope * (float)(j - irow)) : NEG_BIG;
                pvv[c][r] = vsc;
                best = fmaxf(best, vsc);
            }
            best = fmaxf(best, __shfl_xor(best, 1));
            best = fmaxf(best, __shfl_xor(best, 2));
            best = fmaxf(best, __shfl_xor(best, 4));
            best = fmaxf(best, __shfl_xor(best, 8));
            const float mn = fmaxf(mrow[r], best);
            alpha[r] = __expf(mrow[r] - mn);
            mrow[r] = mn;
            float s = 0.f;
            #pragma unroll
            for (int c = 0; c < 2; ++c) {
                const float p = __expf(pvv[c][r] - mn);
                pvv[c][r] = p;
                s += p;
            }
            s += __shfl_xor(s, 1);
            s += __shfl_xor(s, 2);
            s += __shfl_xor(s, 4);
            s += __shfl_xor(s, 8);
            lsum[r] = lsum[r] * alpha[r] + s;
        }

        #pragma unroll
        for (int f = 0; f < 8; ++f)
            #pragma unroll
            for (int r = 0; r < 4; ++r)
                oacc[f][r] *= alpha[r];

        // P -> per-wave LDS (bf16); wave-local, so no block barrier needed
        #pragma unroll
        for (int c = 0; c < 2; ++c)
            #pragma unroll
            for (int r = 0; r < 4; ++r)
                Psl[w][rowg + r][c * 16 + lrow] = f2b(pvv[c][r]);
        asm volatile("s_waitcnt lgkmcnt(0)" ::: "memory");

        bf16x8 pf = *reinterpret_cast<const bf16x8*>(&Psl[w][lrow][lko]);
        #pragma unroll
        for (int nb = 0; nb < 8; ++nb) {
            bf16x8 vf = *reinterpret_cast<const bf16x8*>(&Vt[nb * 16 + lrow][lko]);
            oacc[nb] = __builtin_amdgcn_mfma_f32_16x16x32_bf16(pf, vf, oacc[nb], 0, 0, 0);
        }
    }

    #pragma unroll
    for (int nb = 0; nb < 8; ++nb)
        #pragma unroll
        for (int r = 0; r < 4; ++r) {
            const int row = q0 + rowg + r;
            const int col = h * 128 + nb * 16 + lrow;
            const float vo = oacc[nb][r] / lsum[r];
            const size_t idx = (size_t)(b * 2048 + row) * 2048 + col;
            unsigned short hh = f2b(vo);
            AOh[idx] = hh;
            AOl[idx] = f2b(vo - b2f(hh));
        }
}

extern "C" void kernel_launch(void* const* d_in, const int* in_sizes, int n_in,
                              void* d_out, int out_size, void* d_ws, size_t ws_size,
                              hipStream_t stream)
{
    const float* x   = (const float*)d_in[0];  // (2,2048,2048)
    const float* Wq  = (const float*)d_in[1];  // (2048,2048)
    const float* Wkv = (const float*)d_in[2];  // (2048,1024)
    const float* Wo  = (const float*)d_in[3];  // (2048,2048)
    const float* bo  = (const float*)d_in[4];  // (2048,)

    char* ws = (char*)d_ws;
    unsigned short* xhi = (unsigned short*)(ws + (size_t)0);          // 16MB (later AO hi)
    unsigned short* xlo = (unsigned short*)(ws + ((size_t)16 << 20)); // 16MB (later AO lo)
    unsigned short* Wth = (unsigned short*)(ws + ((size_t)32 << 20)); // 8MB
    unsigned short* Wtl = (unsigned short*)(ws + ((size_t)40 << 20)); // 8MB
    unsigned short* Qb  = (unsigned short*)(ws + ((size_t)48 << 20)); // 16MB
    unsigned short* KVb = (unsigned short*)(ws + ((size_t)64 << 20)); // 8MB
    // total 72MB

    // x -> hi/lo bf16
    k_convert_split<<<8192, 256, 0, stream>>>(x, xhi, xlo, (2 * 2048 * 2048) / 4);

    // Q = x @ Wq           (4096 x 2048 x 2048)
    k_transpose_split<<<dim3(32, 32), 256, 0, stream>>>(Wq, Wth, Wtl, 2048, 2048);
    k_gemm_split<<<dim3(16, 32), 256, 0, stream>>>(xhi, xlo, Wth, Wtl, Qb, nullptr,
                                                   4096, 2048, 2048, 0);
    // KV = x @ Wkv         (4096 x 1024 x 2048)
    k_transpose_split<<<dim3(16, 32), 256, 0, stream>>>(Wkv, Wth, Wtl, 2048, 1024);
    k_gemm_split<<<dim3(8, 32), 256, 0, stream>>>(xhi, xlo, Wth, Wtl, KVb, nullptr,
                                                  4096, 1024, 2048, 0);
    // attention -> AO (reuses x buffers)
    k_attn<<<1024, 256, 0, stream>>>(Qb, KVb, xhi, xlo);

    // out = AO @ Wo + bo   (4096 x 2048 x 2048), f32 out
    k_transpose_split<<<dim3(32, 32), 256, 0, stream>>>(Wo, Wth, Wtl, 2048, 2048);
    k_gemm_split<<<dim3(16, 32), 256, 0, stream>>>(xhi, xlo, Wth, Wtl, d_out, bo,
                                                   4096, 2048, 2048, 1);
}

// Round 3
// 508.949 us; speedup vs baseline: 1.3943x; 1.0259x over previous
//
#include <hip/hip_runtime.h>

typedef __attribute__((ext_vector_type(8))) __bf16 bf16x8;
typedef __attribute__((ext_vector_type(4))) float f32x4;

#define NEG_BIG (-1e30f)

__device__ __forceinline__ unsigned short f2b(float f) {
    unsigned int u = __float_as_uint(f);
    u += 0x7FFFu + ((u >> 16) & 1u);
    return (unsigned short)(u >> 16);
}
__device__ __forceinline__ float b2f(unsigned short h) {
    return __uint_as_float(((unsigned int)h) << 16);
}

typedef const __attribute__((address_space(1))) unsigned int* gas_ptr;
typedef __attribute__((address_space(3))) unsigned int* las_ptr;
__device__ __forceinline__ void gload16(const void* g, void* l) {
    __builtin_amdgcn_global_load_lds((gas_ptr)g, (las_ptr)l, 16, 0, 0);
}

// ---------------- elementwise f32 -> (hi, lo) bf16 split ----------------
__global__ __launch_bounds__(256) void k_convert_split(
    const float* __restrict__ x, unsigned short* __restrict__ hi,
    unsigned short* __restrict__ lo, int n4)
{
    int i = blockIdx.x * 256 + threadIdx.x;
    if (i >= n4) return;
    float4 v = reinterpret_cast<const float4*>(x)[i];
    ushort4 h, l;
    h.x = f2b(v.x); l.x = f2b(v.x - b2f(h.x));
    h.y = f2b(v.y); l.y = f2b(v.y - b2f(h.y));
    h.z = f2b(v.z); l.z = f2b(v.z - b2f(h.z));
    h.w = f2b(v.w); l.w = f2b(v.w - b2f(h.w));
    reinterpret_cast<ushort4*>(hi)[i] = h;
    reinterpret_cast<ushort4*>(lo)[i] = l;
}

// ------------- W (K x N, f32) -> Wt (N x K) hi/lo bf16 -------------
__global__ __launch_bounds__(256) void k_transpose_split(
    const float* __restrict__ W, unsigned short* __restrict__ Th,
    unsigned short* __restrict__ Tl, int K, int N)
{
    __shared__ float tile[64][65];
    const int n0 = blockIdx.x * 64, k0 = blockIdx.y * 64;
    const int c = threadIdx.x & 63, r0 = threadIdx.x >> 6;
    for (int rr = r0; rr < 64; rr += 4)
        tile[rr][c] = W[(size_t)(k0 + rr) * N + n0 + c];
    __syncthreads();
    for (int rr = r0; rr < 64; rr += 4) {
        float v = tile[c][rr];
        unsigned short h = f2b(v);
        size_t idx = (size_t)(n0 + rr) * K + k0 + c;
        Th[idx] = h;
        Tl[idx] = f2b(v - b2f(h));
    }
}

// ------------- split-bf16 GEMM: C = A * B^T(stored [N][K]) -------------
__global__ __launch_bounds__(256) void k_gemm_split(
    const unsigned short* __restrict__ Ah, const unsigned short* __restrict__ Al,
    const unsigned short* __restrict__ Bh, const unsigned short* __restrict__ Bl,
    void* __restrict__ Cout, const float* __restrict__ bias,
    int M, int N, int K, int outF32)
{
    __shared__ __align__(16) unsigned short Ahs[128][32];
    __shared__ __align__(16) unsigned short Als[128][32];
    __shared__ __align__(16) unsigned short Bhs[128][32];
    __shared__ __align__(16) unsigned short Bls[128][32];

    const int tid  = threadIdx.x;
    const int lane = tid & 63, wid = tid >> 6;
    const int wr = wid >> 1, wc = wid & 1;
    const int lrow = lane & 15, lko = (lane >> 4) << 3;
    const int trow = tid >> 2, tk = (tid & 3) << 3;
    const int bm = blockIdx.y, bn = blockIdx.x;
    const int wbyte = wid * 1024;   // lane-linear: thread t -> byte 16*t

    f32x4 acc[4][4] = {};

    const size_t aoff = (size_t)(bm * 128 + trow) * K + tk;
    const size_t boff = (size_t)(bn * 128 + trow) * K + tk;
    const size_t half = (size_t)64 * K;

    for (int k0 = 0; k0 < K; k0 += 32) {
        gload16(&Ah[aoff + k0],        (char*)&Ahs[0][0] + wbyte);
        gload16(&Ah[aoff + half + k0], (char*)&Ahs[0][0] + 4096 + wbyte);
        gload16(&Al[aoff + k0],        (char*)&Als[0][0] + wbyte);
        gload16(&Al[aoff + half + k0], (char*)&Als[0][0] + 4096 + wbyte);
        gload16(&Bh[boff + k0],        (char*)&Bhs[0][0] + wbyte);
        gload16(&Bh[boff + half + k0], (char*)&Bhs[0][0] + 4096 + wbyte);
        gload16(&Bl[boff + k0],        (char*)&Bls[0][0] + wbyte);
        gload16(&Bl[boff + half + k0], (char*)&Bls[0][0] + 4096 + wbyte);
        __syncthreads();

        bf16x8 ahf[4], alf[4], bhf[4], blf[4];
        #pragma unroll
        for (int m = 0; m < 4; ++m) {
            ahf[m] = *reinterpret_cast<const bf16x8*>(&Ahs[wr * 64 + m * 16 + lrow][lko]);
            alf[m] = *reinterpret_cast<const bf16x8*>(&Als[wr * 64 + m * 16 + lrow][lko]);
        }
        #pragma unroll
        for (int n = 0; n < 4; ++n) {
            bhf[n] = *reinterpret_cast<const bf16x8*>(&Bhs[wc * 64 + n * 16 + lrow][lko]);
            blf[n] = *reinterpret_cast<const bf16x8*>(&Bls[wc * 64 + n * 16 + lrow][lko]);
        }
        #pragma unroll
        for (int m = 0; m < 4; ++m)
            #pragma unroll
            for (int n = 0; n < 4; ++n) {
                acc[m][n] = __builtin_amdgcn_mfma_f32_16x16x32_bf16(ahf[m], bhf[n], acc[m][n], 0, 0, 0);
                acc[m][n] = __builtin_amdgcn_mfma_f32_16x16x32_bf16(ahf[m], blf[n], acc[m][n], 0, 0, 0);
                acc[m][n] = __builtin_amdgcn_mfma_f32_16x16x32_bf16(alf[m], bhf[n], acc[m][n], 0, 0, 0);
            }
        __syncthreads();
    }

    const int rbase = bm * 128 + wr * 64 + ((lane >> 4) << 2);
    const int cbase = bn * 128 + wc * 64 + lrow;
    #pragma unroll
    for (int m = 0; m < 4; ++m)
        #pragma unroll
        for (int n = 0; n < 4; ++n) {
            const int col = cbase + n * 16;
            const float bv = bias ? bias[col] : 0.0f;
            #pragma unroll
            for (int r = 0; r < 4; ++r) {
                const size_t idx = (size_t)(rbase + m * 16 + r) * N + col;
                const float v = acc[m][n][r] + bv;
                if (outF32) ((float*)Cout)[idx] = v;
                else        ((unsigned short*)Cout)[idx] = f2b(v);
            }
        }
}

// ------------- fused causal GQA attention with ALiBi -------------
// block = (b, g, tile-pair p): processes q-tiles p and 127-p sequentially
// (uniform work). 4 waves = 4 q-heads sharing kv head g. KVBLK=64,
// double-buffered K (XOR-swizzled, global_load_lds) and V (gather-transpose,
// issue-early/write-late). P per-wave.
__global__ __launch_bounds__(256) void k_attn(
    const unsigned short* __restrict__ Qb,   // (B*T) x 2048 bf16
    const unsigned short* __restrict__ KVb,  // (B*T) x 1024 bf16 (k | v)
    unsigned short* __restrict__ AOh,        // (B*T) x 2048 bf16 hi
    unsigned short* __restrict__ AOl)        // (B*T) x 2048 bf16 lo
{
    __shared__ __align__(16) unsigned short Ksl[2][64][128]; // swizzled
    __shared__ __align__(16) unsigned short Vt[2][128][72];  // [dim][key], padded
    __shared__ __align__(16) unsigned short Psl[4][16][72];

    const int blk = blockIdx.x;
    const int p  = blk & 63;
    const int g  = (blk >> 6) & 3;
    const int b  = blk >> 8;

    const int tid = threadIdx.x;
    const int lane = tid & 63;
    const int w = tid >> 6;          // rep index r
    const int h = w * 4 + g;         // query head
    const float slope = exp2f(-0.5f * (float)(h + 1));
    const float isq = 0.088388347648318447f; // 1/sqrt(128)
    const int lrow = lane & 15;
    const int lko  = (lane >> 4) << 3;
    const int rowg = (lane >> 4) << 2;
    const int skey = tid >> 4;                 // 0..15
    const int sd0  = (tid & 15) << 3;          // 0..120
    const int vdim = tid & 127;                // V gather: dim
    const int vkg  = tid >> 7;                 // V gather: key-group parity

    unsigned short vv[4][8];                   // in-flight V tile (regs)

    auto stageK = [&](int kb, int buf) {
        const int j0 = kb << 6;
        #pragma unroll
        for (int pp = 0; pp < 4; ++pp) {
            const int key = skey + pp * 16;
            const int ds  = sd0 ^ ((key & 7) << 3);
            const size_t off = (size_t)(b * 2048 + j0 + key) * 1024 + g * 128 + ds;
            gload16(&KVb[off], (char*)&Ksl[buf][0][0] + pp * 4096 + w * 1024);
        }
    };
    auto gatherV = [&](int kb) {
        const int j0 = kb << 6;
        #pragma unroll
        for (int gi = 0; gi < 4; ++gi) {
            const int kgi = gi * 2 + vkg;
            const size_t base = (size_t)(b * 2048 + j0 + kgi * 8) * 1024 + 512 + g * 128 + vdim;
            #pragma unroll
            for (int j = 0; j < 8; ++j)
                vv[gi][j] = KVb[base + (size_t)j * 1024];
        }
    };
    auto writeV = [&](int buf) {
        #pragma unroll
        for (int gi = 0; gi < 4; ++gi) {
            const int kgi = gi * 2 + vkg;
            *reinterpret_cast<uint4*>(&Vt[buf][vdim][kgi * 8]) =
                *reinterpret_cast<const uint4*>(&vv[gi][0]);
        }
    };

    for (int half = 0; half < 2; ++half) {
        const int qt = half ? (127 - p) : p;
        const int q0 = qt * 16;

        bf16x8 qf[4];
        {
            const size_t qoff = (size_t)(b * 2048 + q0 + lrow) * 2048 + h * 128 + lko;
            #pragma unroll
            for (int kk = 0; kk < 4; ++kk)
                qf[kk] = *reinterpret_cast<const bf16x8*>(&Qb[qoff + kk * 32]);
        }

        f32x4 oacc[8] = {};
        float mrow[4] = {NEG_BIG, NEG_BIG, NEG_BIG, NEG_BIG};
        float lsum[4] = {0.f, 0.f, 0.f, 0.f};
        const int nkb = (q0 + 16 + 63) >> 6;

        // prologue: stage tile 0 into buffer 0
        stageK(0, 0);
        gatherV(0);
        asm volatile("s_waitcnt vmcnt(0)" ::: "memory");
        writeV(0);
        __syncthreads();

        int cur = 0;
        for (int kb = 0; kb < nkb; ++kb, cur ^= 1) {
            const int j0 = kb << 6;
            const bool pre = (kb + 1 < nkb);
            if (pre) { stageK(kb + 1, cur ^ 1); gatherV(kb + 1); }

            // S = Q K^T : 16 q-rows x 64 keys
            f32x4 sa[4] = {};
            #pragma unroll
            for (int c = 0; c < 4; ++c) {
                const int krow = c * 16 + lrow;
                #pragma unroll
                for (int kk = 0; kk < 4; ++kk) {
                    bf16x8 kf = *reinterpret_cast<const bf16x8*>(
                        &Ksl[cur][krow][(kk * 32 + lko) ^ ((krow & 7) << 3)]);
                    sa[c] = __builtin_amdgcn_mfma_f32_16x16x32_bf16(qf[kk], kf, sa[c], 0, 0, 0);
                }
            }

            float pvv[4][4], alpha[4];
            #pragma unroll
            for (int r = 0; r < 4; ++r) {
                const int irow = q0 + rowg + r;
                float best = NEG_BIG;
                #pragma unroll
                for (int c = 0; c < 4; ++c) {
                    const int j = j0 + c * 16 + lrow;
                    float vsc = (j <= irow) ? (sa[c][r] * isq + slope * (float)(j - irow)) : NEG_BIG;
                    pvv[c][r] = vsc;
                    best = fmaxf(best, vsc);
                }
                best = fmaxf(best, __shfl_xor(best, 1));
                best = fmaxf(best, __shfl_xor(best, 2));
                best = fmaxf(best, __shfl_xor(best, 4));
                best = fmaxf(best, __shfl_xor(best, 8));
                const float mn = fmaxf(mrow[r], best);
                alpha[r] = __expf(mrow[r] - mn);
                mrow[r] = mn;
                float s = 0.f;
                #pragma unroll
                for (int c = 0; c < 4; ++c) {
                    const float pe = __expf(pvv[c][r] - mn);
                    pvv[c][r] = pe;
                    s += pe;
                }
                s += __shfl_xor(s, 1);
                s += __shfl_xor(s, 2);
                s += __shfl_xor(s, 4);
                s += __shfl_xor(s, 8);
                lsum[r] = lsum[r] * alpha[r] + s;
            }

            #pragma unroll
            for (int f = 0; f < 8; ++f)
                #pragma unroll
                for (int r = 0; r < 4; ++r)
                    oacc[f][r] *= alpha[r];

            // P -> per-wave LDS (bf16)
            #pragma unroll
            for (int c = 0; c < 4; ++c)
                #pragma unroll
                for (int r = 0; r < 4; ++r)
                    Psl[w][rowg + r][c * 16 + lrow] = f2b(pvv[c][r]);
            asm volatile("s_waitcnt lgkmcnt(0)" ::: "memory");

            #pragma unroll
            for (int kk2 = 0; kk2 < 2; ++kk2) {
                bf16x8 pf = *reinterpret_cast<const bf16x8*>(&Psl[w][lrow][kk2 * 32 + lko]);
                #pragma unroll
                for (int nb = 0; nb < 8; ++nb) {
                    bf16x8 vf = *reinterpret_cast<const bf16x8*>(&Vt[cur][nb * 16 + lrow][kk2 * 32 + lko]);
                    oacc[nb] = __builtin_amdgcn_mfma_f32_16x16x32_bf16(pf, vf, oacc[nb], 0, 0, 0);
                }
            }

            if (pre) {
                asm volatile("s_waitcnt vmcnt(0)" ::: "memory");
                writeV(cur ^ 1);
            }
            __syncthreads();
        }

        // epilogue: write AO rows for this q-tile
        #pragma unroll
        for (int nb = 0; nb < 8; ++nb)
            #pragma unroll
            for (int r = 0; r < 4; ++r) {
                const int row = q0 + rowg + r;
                const int col = h * 128 + nb * 16 + lrow;
                const float vo = oacc[nb][r] / lsum[r];
                const size_t idx = (size_t)(b * 2048 + row) * 2048 + col;
                unsigned short hh = f2b(vo);
                AOh[idx] = hh;
                AOl[idx] = f2b(vo - b2f(hh));
            }
    }
}

extern "C" void kernel_launch(void* const* d_in, const int* in_sizes, int n_in,
                              void* d_out, int out_size, void* d_ws, size_t ws_size,
                              hipStream_t stream)
{
    const float* x   = (const float*)d_in[0];  // (2,2048,2048)
    const float* Wq  = (const float*)d_in[1];  // (2048,2048)
    const float* Wkv = (const float*)d_in[2];  // (2048,1024)
    const float* Wo  = (const float*)d_in[3];  // (2048,2048)
    const float* bo  = (const float*)d_in[4];  // (2048,)

    char* ws = (char*)d_ws;
    unsigned short* xhi = (unsigned short*)(ws + (size_t)0);          // 16MB (later AO hi)
    unsigned short* xlo = (unsigned short*)(ws + ((size_t)16 << 20)); // 16MB (later AO lo)
    unsigned short* Wth = (unsigned short*)(ws + ((size_t)32 << 20)); // 8MB
    unsigned short* Wtl = (unsigned short*)(ws + ((size_t)40 << 20)); // 8MB
    unsigned short* Qb  = (unsigned short*)(ws + ((size_t)48 << 20)); // 16MB
    unsigned short* KVb = (unsigned short*)(ws + ((size_t)64 << 20)); // 8MB
    // total 72MB

    // x -> hi/lo bf16
    k_convert_split<<<8192, 256, 0, stream>>>(x, xhi, xlo, (2 * 2048 * 2048) / 4);

    // Q = x @ Wq           (4096 x 2048 x 2048)
    k_transpose_split<<<dim3(32, 32), 256, 0, stream>>>(Wq, Wth, Wtl, 2048, 2048);
    k_gemm_split<<<dim3(16, 32), 256, 0, stream>>>(xhi, xlo, Wth, Wtl, Qb, nullptr,
                                                   4096, 2048, 2048, 0);
    // KV = x @ Wkv         (4096 x 1024 x 2048)
    k_transpose_split<<<dim3(16, 32), 256, 0, stream>>>(Wkv, Wth, Wtl, 2048, 1024);
    k_gemm_split<<<dim3(8, 32), 256, 0, stream>>>(xhi, xlo, Wth, Wtl, KVb, nullptr,
                                                  4096, 1024, 2048, 0);
    // attention -> AO (reuses x buffers)
    k_attn<<<512, 256, 0, stream>>>(Qb, KVb, xhi, xlo);

    // out = AO @ Wo + bo   (4096 x 2048 x 2048), f32 out
    k_transpose_split<<<dim3(32, 32), 256, 0, stream>>>(Wo, Wth, Wtl, 2048, 2048);
    k_gemm_split<<<dim3(16, 32), 256, 0, stream>>>(xhi, xlo, Wth, Wtl, d_out, bo,
                                                   4096, 2048, 2048, 1);
}

// Round 4
// 454.431 us; speedup vs baseline: 1.5615x; 1.1200x over previous
//
#include <hip/hip_runtime.h>

typedef __attribute__((ext_vector_type(8))) __bf16 bf16x8;
typedef __attribute__((ext_vector_type(4))) float f32x4;

#define NEG_BIG (-1e30f)

__device__ __forceinline__ unsigned short f2b(float f) {
    unsigned int u = __float_as_uint(f);
    u += 0x7FFFu + ((u >> 16) & 1u);
    return (unsigned short)(u >> 16);
}
__device__ __forceinline__ float b2f(unsigned short h) {
    return __uint_as_float(((unsigned int)h) << 16);
}
__device__ __forceinline__ unsigned cvtpk(float lo, float hi) {
    unsigned r;
    asm("v_cvt_pk_bf16_f32 %0, %1, %2" : "=v"(r) : "v"(lo), "v"(hi));
    return r;
}

typedef const __attribute__((address_space(1))) unsigned int* gas_ptr;
typedef __attribute__((address_space(3))) unsigned int* las_ptr;
__device__ __forceinline__ void gload16(const void* g, void* l) {
    __builtin_amdgcn_global_load_lds((gas_ptr)g, (las_ptr)l, 16, 0, 0);
}

// ---------------- elementwise f32 -> (hi, lo) bf16 split ----------------
__global__ __launch_bounds__(256) void k_convert_split(
    const float* __restrict__ x, unsigned short* __restrict__ hi,
    unsigned short* __restrict__ lo, int n4)
{
    int i = blockIdx.x * 256 + threadIdx.x;
    if (i >= n4) return;
    float4 v = reinterpret_cast<const float4*>(x)[i];
    ushort4 h, l;
    h.x = f2b(v.x); l.x = f2b(v.x - b2f(h.x));
    h.y = f2b(v.y); l.y = f2b(v.y - b2f(h.y));
    h.z = f2b(v.z); l.z = f2b(v.z - b2f(h.z));
    h.w = f2b(v.w); l.w = f2b(v.w - b2f(h.w));
    reinterpret_cast<ushort4*>(hi)[i] = h;
    reinterpret_cast<ushort4*>(lo)[i] = l;
}

// ------------- W (K x N, f32) -> Wt (N x K) hi/lo bf16 -------------
__global__ __launch_bounds__(256) void k_transpose_split(
    const float* __restrict__ W, unsigned short* __restrict__ Th,
    unsigned short* __restrict__ Tl, int K, int N)
{
    __shared__ float tile[64][65];
    const int n0 = blockIdx.x * 64, k0 = blockIdx.y * 64;
    const int c = threadIdx.x & 63, r0 = threadIdx.x >> 6;
    for (int rr = r0; rr < 64; rr += 4)
        tile[rr][c] = W[(size_t)(k0 + rr) * N + n0 + c];
    __syncthreads();
    for (int rr = r0; rr < 64; rr += 4) {
        float v = tile[c][rr];
        unsigned short h = f2b(v);
        size_t idx = (size_t)(n0 + rr) * K + k0 + c;
        Th[idx] = h;
        Tl[idx] = f2b(v - b2f(h));
    }
}

// ------------- split-bf16 GEMM: C = A * B^T(stored [N][K]) -------------
__global__ __launch_bounds__(256) void k_gemm_split(
    const unsigned short* __restrict__ Ah, const unsigned short* __restrict__ Al,
    const unsigned short* __restrict__ Bh, const unsigned short* __restrict__ Bl,
    void* __restrict__ Cout, const float* __restrict__ bias,
    int M, int N, int K, int outF32)
{
    __shared__ __align__(16) unsigned short Ahs[128][32];
    __shared__ __align__(16) unsigned short Als[128][32];
    __shared__ __align__(16) unsigned short Bhs[128][32];
    __shared__ __align__(16) unsigned short Bls[128][32];

    const int tid  = threadIdx.x;
    const int lane = tid & 63, wid = tid >> 6;
    const int wr = wid >> 1, wc = wid & 1;
    const int lrow = lane & 15, lko = (lane >> 4) << 3;
    const int trow = tid >> 2, tk = (tid & 3) << 3;
    const int bm = blockIdx.y, bn = blockIdx.x;
    const int wbyte = wid * 1024;   // lane-linear: thread t -> byte 16*t

    f32x4 acc[4][4] = {};

    const size_t aoff = (size_t)(bm * 128 + trow) * K + tk;
    const size_t boff = (size_t)(bn * 128 + trow) * K + tk;
    const size_t half = (size_t)64 * K;

    for (int k0 = 0; k0 < K; k0 += 32) {
        gload16(&Ah[aoff + k0],        (char*)&Ahs[0][0] + wbyte);
        gload16(&Ah[aoff + half + k0], (char*)&Ahs[0][0] + 4096 + wbyte);
        gload16(&Al[aoff + k0],        (char*)&Als[0][0] + wbyte);
        gload16(&Al[aoff + half + k0], (char*)&Als[0][0] + 4096 + wbyte);
        gload16(&Bh[boff + k0],        (char*)&Bhs[0][0] + wbyte);
        gload16(&Bh[boff + half + k0], (char*)&Bhs[0][0] + 4096 + wbyte);
        gload16(&Bl[boff + k0],        (char*)&Bls[0][0] + wbyte);
        gload16(&Bl[boff + half + k0], (char*)&Bls[0][0] + 4096 + wbyte);
        __syncthreads();

        bf16x8 ahf[4], alf[4], bhf[4], blf[4];
        #pragma unroll
        for (int m = 0; m < 4; ++m) {
            ahf[m] = *reinterpret_cast<const bf16x8*>(&Ahs[wr * 64 + m * 16 + lrow][lko]);
            alf[m] = *reinterpret_cast<const bf16x8*>(&Als[wr * 64 + m * 16 + lrow][lko]);
        }
        #pragma unroll
        for (int n = 0; n < 4; ++n) {
            bhf[n] = *reinterpret_cast<const bf16x8*>(&Bhs[wc * 64 + n * 16 + lrow][lko]);
            blf[n] = *reinterpret_cast<const bf16x8*>(&Bls[wc * 64 + n * 16 + lrow][lko]);
        }
        #pragma unroll
        for (int m = 0; m < 4; ++m)
            #pragma unroll
            for (int n = 0; n < 4; ++n) {
                acc[m][n] = __builtin_amdgcn_mfma_f32_16x16x32_bf16(ahf[m], bhf[n], acc[m][n], 0, 0, 0);
                acc[m][n] = __builtin_amdgcn_mfma_f32_16x16x32_bf16(ahf[m], blf[n], acc[m][n], 0, 0, 0);
                acc[m][n] = __builtin_amdgcn_mfma_f32_16x16x32_bf16(alf[m], bhf[n], acc[m][n], 0, 0, 0);
            }
        __syncthreads();
    }

    const int rbase = bm * 128 + wr * 64 + ((lane >> 4) << 2);
    const int cbase = bn * 128 + wc * 64 + lrow;
    #pragma unroll
    for (int m = 0; m < 4; ++m)
        #pragma unroll
        for (int n = 0; n < 4; ++n) {
            const int col = cbase + n * 16;
            const float bv = bias ? bias[col] : 0.0f;
            #pragma unroll
            for (int r = 0; r < 4; ++r) {
                const size_t idx = (size_t)(rbase + m * 16 + r) * N + col;
                const float v = acc[m][n][r] + bv;
                if (outF32) ((float*)Cout)[idx] = v;
                else        ((unsigned short*)Cout)[idx] = f2b(v);
            }
        }
}

// ------------- fused causal GQA attention with ALiBi -------------
// block = (b, g, qt), work-descending launch order. 4 waves = 4 q-heads
// sharing kv head g. KVBLK=64, single-buffered K (XOR-swizzled, reg-staged
// early-issue/late-write) and V (gather-transpose, same). Swapped QK^T:
// each lane owns one q-row -> in-lane softmax (2 shfls per reduce).
__global__ __launch_bounds__(256, 3) void k_attn(
    const unsigned short* __restrict__ Qb,   // (B*T) x 2048 bf16
    const unsigned short* __restrict__ KVb,  // (B*T) x 1024 bf16 (k | v)
    unsigned short* __restrict__ AOh,        // (B*T) x 2048 bf16 hi
    unsigned short* __restrict__ AOl)        // (B*T) x 2048 bf16 lo
{
    __shared__ __align__(16) unsigned short Ksl[64][128]; // [key][dim ^ ((key&7)<<3)]
    __shared__ __align__(16) unsigned short Vt[128][72];  // [dim][key], padded
    __shared__ __align__(16) unsigned short Psl[4][16][72];

    const int blk = blockIdx.x;
    const int ord = blk >> 3;          // 0..127, descending work
    const int sub = blk & 7;
    const int b   = sub >> 2;
    const int g   = sub & 3;
    const int qt  = 127 - ord;
    const int q0  = qt * 16;

    const int tid = threadIdx.x;
    const int lane = tid & 63;
    const int w = tid >> 6;          // rep index r
    const int h = w * 4 + g;         // query head
    const float slope = exp2f(-0.5f * (float)(h + 1));
    const float isq = 0.088388347648318447f; // 1/sqrt(128)
    const int lrow = lane & 15;
    const int lko  = (lane >> 4) << 3;
    const int rowg = (lane >> 4) << 2;
    const int skey = tid >> 4;                 // 0..15
    const int sd0  = (tid & 15) << 3;          // 0..120
    const int vdim = tid & 127;                // V gather: dim
    const int vkg  = tid >> 7;                 // V gather: key-group parity

    uint4 kreg[4];                             // in-flight K tile (regs)
    unsigned short vv[4][8];                   // in-flight V tile (regs)

    auto ldK = [&](int kb) {
        const int j0 = kb << 6;
        #pragma unroll
        for (int pp = 0; pp < 4; ++pp) {
            const int key = skey + pp * 16;
            kreg[pp] = *reinterpret_cast<const uint4*>(
                &KVb[(size_t)(b * 2048 + j0 + key) * 1024 + g * 128 + sd0]);
        }
    };
    auto wrK = [&]() {
        #pragma unroll
        for (int pp = 0; pp < 4; ++pp) {
            const int key = skey + pp * 16;
            *reinterpret_cast<uint4*>(&Ksl[key][sd0 ^ ((key & 7) << 3)]) = kreg[pp];
        }
    };
    auto ldV = [&](int kb) {
        const int j0 = kb << 6;
        #pragma unroll
        for (int gi = 0; gi < 4; ++gi) {
            const int kgi = gi * 2 + vkg;
            const size_t base = (size_t)(b * 2048 + j0 + kgi * 8) * 1024 + 512 + g * 128 + vdim;
            #pragma unroll
            for (int j = 0; j < 8; ++j)
                vv[gi][j] = KVb[base + (size_t)j * 1024];
        }
    };
    auto wrV = [&]() {
        #pragma unroll
        for (int gi = 0; gi < 4; ++gi) {
            const int kgi = gi * 2 + vkg;
            *reinterpret_cast<uint4*>(&Vt[vdim][kgi * 8]) =
                *reinterpret_cast<const uint4*>(&vv[gi][0]);
        }
    };

    bf16x8 qf[4];
    {
        const size_t qoff = (size_t)(b * 2048 + q0 + lrow) * 2048 + h * 128 + lko;
        #pragma unroll
        for (int kk = 0; kk < 4; ++kk)
            qf[kk] = *reinterpret_cast<const bf16x8*>(&Qb[qoff + kk * 32]);
    }

    f32x4 oacc[8] = {};
    float mrow = NEG_BIG, lsum = 0.f;
    const int nkb = (q0 + 16 + 63) >> 6;
    const int q = q0 + lrow;                   // this lane's q-row

    // prologue: stage tile 0
    ldK(0); ldV(0);
    wrK(); wrV();
    __syncthreads();

    for (int kb = 0; kb < nkb; ++kb) {
        const int j0 = kb << 6;
        const bool pre = (kb + 1 < nkb);
        if (pre) { ldK(kb + 1); ldV(kb + 1); }

        // S^T = K Q^T : lane owns q-row q, 16 keys in regs
        f32x4 sa[4] = {};
        #pragma unroll
        for (int c = 0; c < 4; ++c) {
            const int krow = c * 16 + lrow;
            #pragma unroll
            for (int kk = 0; kk < 4; ++kk) {
                bf16x8 kf = *reinterpret_cast<const bf16x8*>(
                    &Ksl[krow][(kk * 32 + lko) ^ ((krow & 7) << 3)]);
                sa[c] = __builtin_amdgcn_mfma_f32_16x16x32_bf16(kf, qf[kk], sa[c], 0, 0, 0);
            }
        }

        // in-lane softmax over 16 values (one q-row per lane)
        float pv[4][4];
        float mt = NEG_BIG;
        #pragma unroll
        for (int c = 0; c < 4; ++c)
            #pragma unroll
            for (int r = 0; r < 4; ++r) {
                const int j = j0 + c * 16 + rowg + r;
                const float vsc = (j <= q) ? (sa[c][r] * isq + slope * (float)(j - q)) : NEG_BIG;
                pv[c][r] = vsc;
                mt = fmaxf(mt, vsc);
            }
        mt = fmaxf(mt, __shfl_xor(mt, 16));
        mt = fmaxf(mt, __shfl_xor(mt, 32));
        const float mn = fmaxf(mrow, mt);
        const float alpha = __expf(mrow - mn);
        mrow = mn;
        float s = 0.f;
        #pragma unroll
        for (int c = 0; c < 4; ++c)
            #pragma unroll
            for (int r = 0; r < 4; ++r) {
                const float pe = __expf(pv[c][r] - mn);
                pv[c][r] = pe;
                s += pe;
            }
        s += __shfl_xor(s, 16);
        s += __shfl_xor(s, 32);
        lsum = lsum * alpha + s;

        // redistribute alpha to PV accumulator rows (q = rowg + r)
        float ar[4];
        #pragma unroll
        for (int r = 0; r < 4; ++r) ar[r] = __shfl(alpha, rowg + r);
        #pragma unroll
        for (int f = 0; f < 8; ++f)
            #pragma unroll
            for (int r = 0; r < 4; ++r)
                oacc[f][r] *= ar[r];

        // P pack (cvt_pk) -> per-wave LDS, b64 writes
        #pragma unroll
        for (int c = 0; c < 4; ++c) {
            uint2 pw;
            pw.x = cvtpk(pv[c][0], pv[c][1]);
            pw.y = cvtpk(pv[c][2], pv[c][3]);
            *reinterpret_cast<uint2*>(&Psl[w][lrow][c * 16 + rowg]) = pw;
        }
        asm volatile("s_waitcnt lgkmcnt(0)" ::: "memory");

        #pragma unroll
        for (int kk2 = 0; kk2 < 2; ++kk2) {
            bf16x8 pf = *reinterpret_cast<const bf16x8*>(&Psl[w][lrow][kk2 * 32 + lko]);
            #pragma unroll
            for (int nb = 0; nb < 8; ++nb) {
                bf16x8 vf = *reinterpret_cast<const bf16x8*>(&Vt[nb * 16 + lrow][kk2 * 32 + lko]);
                oacc[nb] = __builtin_amdgcn_mfma_f32_16x16x32_bf16(pf, vf, oacc[nb], 0, 0, 0);
            }
        }

        __syncthreads();             // all waves done reading Ksl/Vt
        if (pre) { wrK(); wrV(); }
        __syncthreads();             // next tile visible
    }

    // epilogue
    float lr[4];
    #pragma unroll
    for (int r = 0; r < 4; ++r) lr[r] = __shfl(lsum, rowg + r);
    #pragma unroll
    for (int nb = 0; nb < 8; ++nb)
        #pragma unroll
        for (int r = 0; r < 4; ++r) {
            const int row = q0 + rowg + r;
            const int col = h * 128 + nb * 16 + lrow;
            const float vo = oacc[nb][r] / lr[r];
            const size_t idx = (size_t)(b * 2048 + row) * 2048 + col;
            unsigned short hh = f2b(vo);
            AOh[idx] = hh;
            AOl[idx] = f2b(vo - b2f(hh));
        }
}

extern "C" void kernel_launch(void* const* d_in, const int* in_sizes, int n_in,
                              void* d_out, int out_size, void* d_ws, size_t ws_size,
                              hipStream_t stream)
{
    const float* x   = (const float*)d_in[0];  // (2,2048,2048)
    const float* Wq  = (const float*)d_in[1];  // (2048,2048)
    const float* Wkv = (const float*)d_in[2];  // (2048,1024)
    const float* Wo  = (const float*)d_in[3];  // (2048,2048)
    const float* bo  = (const float*)d_in[4];  // (2048,)

    char* ws = (char*)d_ws;
    unsigned short* xhi = (unsigned short*)(ws + (size_t)0);          // 16MB (later AO hi)
    unsigned short* xlo = (unsigned short*)(ws + ((size_t)16 << 20)); // 16MB (later AO lo)
    unsigned short* Wth = (unsigned short*)(ws + ((size_t)32 << 20)); // 8MB
    unsigned short* Wtl = (unsigned short*)(ws + ((size_t)40 << 20)); // 8MB
    unsigned short* Qb  = (unsigned short*)(ws + ((size_t)48 << 20)); // 16MB
    unsigned short* KVb = (unsigned short*)(ws + ((size_t)64 << 20)); // 8MB
    // total 72MB

    // x -> hi/lo bf16
    k_convert_split<<<8192, 256, 0, stream>>>(x, xhi, xlo, (2 * 2048 * 2048) / 4);

    // Q = x @ Wq           (4096 x 2048 x 2048)
    k_transpose_split<<<dim3(32, 32), 256, 0, stream>>>(Wq, Wth, Wtl, 2048, 2048);
    k_gemm_split<<<dim3(16, 32), 256, 0, stream>>>(xhi, xlo, Wth, Wtl, Qb, nullptr,
                                                   4096, 2048, 2048, 0);
    // KV = x @ Wkv         (4096 x 1024 x 2048)
    k_transpose_split<<<dim3(16, 32), 256, 0, stream>>>(Wkv, Wth, Wtl, 2048, 1024);
    k_gemm_split<<<dim3(8, 32), 256, 0, stream>>>(xhi, xlo, Wth, Wtl, KVb, nullptr,
                                                  4096, 1024, 2048, 0);
    // attention -> AO (reuses x buffers)
    k_attn<<<1024, 256, 0, stream>>>(Qb, KVb, xhi, xlo);

    // out = AO @ Wo + bo   (4096 x 2048 x 2048), f32 out
    k_transpose_split<<<dim3(32, 32), 256, 0, stream>>>(Wo, Wth, Wtl, 2048, 2048);
    k_gemm_split<<<dim3(16, 32), 256, 0, stream>>>(xhi, xlo, Wth, Wtl, d_out, bo,
                                                   4096, 2048, 2048, 1);
}

// Round 5
// 305.133 us; speedup vs baseline: 2.3256x; 1.4893x over previous
//
#include <hip/hip_runtime.h>

typedef __attribute__((ext_vector_type(8))) __bf16 bf16x8;
typedef __attribute__((ext_vector_type(4))) float f32x4;

#define NEG_BIG (-1e30f)

__device__ __forceinline__ unsigned short f2b(float f) {
    unsigned int u = __float_as_uint(f);
    u += 0x7FFFu + ((u >> 16) & 1u);
    return (unsigned short)(u >> 16);
}
__device__ __forceinline__ float b2f(unsigned short h) {
    return __uint_as_float(((unsigned int)h) << 16);
}
__device__ __forceinline__ unsigned cvtpk(float lo, float hi) {
    unsigned r;
    asm("v_cvt_pk_bf16_f32 %0, %1, %2" : "=v"(r) : "v"(lo), "v"(hi));
    return r;
}

typedef const __attribute__((address_space(1))) unsigned int* gas_ptr;
typedef __attribute__((address_space(3))) unsigned int* las_ptr;
__device__ __forceinline__ void gload16(const void* g, void* l) {
    __builtin_amdgcn_global_load_lds((gas_ptr)g, (las_ptr)l, 16, 0, 0);
}

// ---------------- elementwise f32 -> bf16 (rn) ----------------
__global__ __launch_bounds__(256) void k_convert(
    const float* __restrict__ x, unsigned short* __restrict__ xb, int n4)
{
    int i = blockIdx.x * 256 + threadIdx.x;
    if (i >= n4) return;
    float4 v = reinterpret_cast<const float4*>(x)[i];
    ushort4 h;
    h.x = f2b(v.x); h.y = f2b(v.y); h.z = f2b(v.z); h.w = f2b(v.w);
    reinterpret_cast<ushort4*>(xb)[i] = h;
}

// ------------- W (K x N, f32) -> Wt (N x K) bf16 -------------
__global__ __launch_bounds__(256) void k_transpose(
    const float* __restrict__ W, unsigned short* __restrict__ Th, int K, int N)
{
    __shared__ float tile[64][65];
    const int n0 = blockIdx.x * 64, k0 = blockIdx.y * 64;
    const int c = threadIdx.x & 63, r0 = threadIdx.x >> 6;
    for (int rr = r0; rr < 64; rr += 4)
        tile[rr][c] = W[(size_t)(k0 + rr) * N + n0 + c];
    __syncthreads();
    for (int rr = r0; rr < 64; rr += 4)
        Th[(size_t)(n0 + rr) * K + k0 + c] = f2b(tile[c][rr]);
}

// ------------- plain bf16 GEMM: C = A * B^T(stored [N][K]) -------------
// 128x128 tile, BK=32, 4 waves (2x2), each wave 64x64 = 4x4 16x16x32 frags.
__global__ __launch_bounds__(256) void k_gemm(
    const unsigned short* __restrict__ A, const unsigned short* __restrict__ B,
    void* __restrict__ Cout, const float* __restrict__ bias,
    int M, int N, int K, int outF32)
{
    __shared__ __align__(16) unsigned short As[128][32];
    __shared__ __align__(16) unsigned short Bs[128][32];

    const int tid  = threadIdx.x;
    const int lane = tid & 63, wid = tid >> 6;
    const int wr = wid >> 1, wc = wid & 1;
    const int lrow = lane & 15, lko = (lane >> 4) << 3;
    const int trow = tid >> 2, tk = (tid & 3) << 3;
    const int bm = blockIdx.y, bn = blockIdx.x;
    const int wbyte = wid * 1024;   // lane-linear: thread t -> byte 16*t

    f32x4 acc[4][4] = {};

    const size_t aoff = (size_t)(bm * 128 + trow) * K + tk;
    const size_t boff = (size_t)(bn * 128 + trow) * K + tk;
    const size_t half = (size_t)64 * K;

    for (int k0 = 0; k0 < K; k0 += 32) {
        gload16(&A[aoff + k0],        (char*)&As[0][0] + wbyte);
        gload16(&A[aoff + half + k0], (char*)&As[0][0] + 4096 + wbyte);
        gload16(&B[boff + k0],        (char*)&Bs[0][0] + wbyte);
        gload16(&B[boff + half + k0], (char*)&Bs[0][0] + 4096 + wbyte);
        __syncthreads();

        bf16x8 af[4], bf[4];
        #pragma unroll
        for (int m = 0; m < 4; ++m)
            af[m] = *reinterpret_cast<const bf16x8*>(&As[wr * 64 + m * 16 + lrow][lko]);
        #pragma unroll
        for (int n = 0; n < 4; ++n)
            bf[n] = *reinterpret_cast<const bf16x8*>(&Bs[wc * 64 + n * 16 + lrow][lko]);
        #pragma unroll
        for (int m = 0; m < 4; ++m)
            #pragma unroll
            for (int n = 0; n < 4; ++n)
                acc[m][n] = __builtin_amdgcn_mfma_f32_16x16x32_bf16(af[m], bf[n], acc[m][n], 0, 0, 0);
        __syncthreads();
    }

    const int rbase = bm * 128 + wr * 64 + ((lane >> 4) << 2);
    const int cbase = bn * 128 + wc * 64 + lrow;
    #pragma unroll
    for (int m = 0; m < 4; ++m)
        #pragma unroll
        for (int n = 0; n < 4; ++n) {
            const int col = cbase + n * 16;
            const float bv = bias ? bias[col] : 0.0f;
            #pragma unroll
            for (int r = 0; r < 4; ++r) {
                const size_t idx = (size_t)(rbase + m * 16 + r) * N + col;
                const float v = acc[m][n][r] + bv;
                if (outF32) ((float*)Cout)[idx] = v;
                else        ((unsigned short*)Cout)[idx] = f2b(v);
            }
        }
}

// ------------- fused causal GQA attention with ALiBi -------------
// block = (b, g, qt), work-descending launch order. 4 waves = 4 q-heads
// sharing kv head g. KVBLK=64, single-buffered K (XOR-swizzled, reg-staged
// early-issue/late-write) and V (gather-transpose, same). Swapped QK^T:
// each lane owns one q-row -> in-lane softmax (2 shfls per reduce).
__global__ __launch_bounds__(256, 3) void k_attn(
    const unsigned short* __restrict__ Qb,   // (B*T) x 2048 bf16
    const unsigned short* __restrict__ KVb,  // (B*T) x 1024 bf16 (k | v)
    unsigned short* __restrict__ AO)         // (B*T) x 2048 bf16
{
    __shared__ __align__(16) unsigned short Ksl[64][128]; // [key][dim ^ ((key&7)<<3)]
    __shared__ __align__(16) unsigned short Vt[128][72];  // [dim][key], padded
    __shared__ __align__(16) unsigned short Psl[4][16][72];

    const int blk = blockIdx.x;
    const int ord = blk >> 3;          // 0..127, descending work
    const int sub = blk & 7;
    const int b   = sub >> 2;
    const int g   = sub & 3;
    const int qt  = 127 - ord;
    const int q0  = qt * 16;

    const int tid = threadIdx.x;
    const int lane = tid & 63;
    const int w = tid >> 6;          // rep index r
    const int h = w * 4 + g;         // query head
    const float slope = exp2f(-0.5f * (float)(h + 1));
    const float isq = 0.088388347648318447f; // 1/sqrt(128)
    const int lrow = lane & 15;
    const int lko  = (lane >> 4) << 3;
    const int rowg = (lane >> 4) << 2;
    const int skey = tid >> 4;                 // 0..15
    const int sd0  = (tid & 15) << 3;          // 0..120
    const int vdim = tid & 127;                // V gather: dim
    const int vkg  = tid >> 7;                 // V gather: key-group parity

    uint4 kreg[4];                             // in-flight K tile (regs)
    unsigned short vv[4][8];                   // in-flight V tile (regs)

    auto ldK = [&](int kb) {
        const int j0 = kb << 6;
        #pragma unroll
        for (int pp = 0; pp < 4; ++pp) {
            const int key = skey + pp * 16;
            kreg[pp] = *reinterpret_cast<const uint4*>(
                &KVb[(size_t)(b * 2048 + j0 + key) * 1024 + g * 128 + sd0]);
        }
    };
    auto wrK = [&]() {
        #pragma unroll
        for (int pp = 0; pp < 4; ++pp) {
            const int key = skey + pp * 16;
            *reinterpret_cast<uint4*>(&Ksl[key][sd0 ^ ((key & 7) << 3)]) = kreg[pp];
        }
    };
    auto ldV = [&](int kb) {
        const int j0 = kb << 6;
        #pragma unroll
        for (int gi = 0; gi < 4; ++gi) {
            const int kgi = gi * 2 + vkg;
            const size_t base = (size_t)(b * 2048 + j0 + kgi * 8) * 1024 + 512 + g * 128 + vdim;
            #pragma unroll
            for (int j = 0; j < 8; ++j)
                vv[gi][j] = KVb[base + (size_t)j * 1024];
        }
    };
    auto wrV = [&]() {
        #pragma unroll
        for (int gi = 0; gi < 4; ++gi) {
            const int kgi = gi * 2 + vkg;
            *reinterpret_cast<uint4*>(&Vt[vdim][kgi * 8]) =
                *reinterpret_cast<const uint4*>(&vv[gi][0]);
        }
    };

    bf16x8 qf[4];
    {
        const size_t qoff = (size_t)(b * 2048 + q0 + lrow) * 2048 + h * 128 + lko;
        #pragma unroll
        for (int kk = 0; kk < 4; ++kk)
            qf[kk] = *reinterpret_cast<const bf16x8*>(&Qb[qoff + kk * 32]);
    }

    f32x4 oacc[8] = {};
    float mrow = NEG_BIG, lsum = 0.f;
    const int nkb = (q0 + 16 + 63) >> 6;
    const int q = q0 + lrow;                   // this lane's q-row

    // prologue: stage tile 0
    ldK(0); ldV(0);
    wrK(); wrV();
    __syncthreads();

    for (int kb = 0; kb < nkb; ++kb) {
        const int j0 = kb << 6;
        const bool pre = (kb + 1 < nkb);
        if (pre) { ldK(kb + 1); ldV(kb + 1); }

        // S^T = K Q^T : lane owns q-row q, 16 keys in regs
        f32x4 sa[4] = {};
        #pragma unroll
        for (int c = 0; c < 4; ++c) {
            const int krow = c * 16 + lrow;
            #pragma unroll
            for (int kk = 0; kk < 4; ++kk) {
                bf16x8 kf = *reinterpret_cast<const bf16x8*>(
                    &Ksl[krow][(kk * 32 + lko) ^ ((krow & 7) << 3)]);
                sa[c] = __builtin_amdgcn_mfma_f32_16x16x32_bf16(kf, qf[kk], sa[c], 0, 0, 0);
            }
        }

        // in-lane softmax over 16 values (one q-row per lane)
        float pv[4][4];
        float mt = NEG_BIG;
        #pragma unroll
        for (int c = 0; c < 4; ++c)
            #pragma unroll
            for (int r = 0; r < 4; ++r) {
                const int j = j0 + c * 16 + rowg + r;
                const float vsc = (j <= q) ? (sa[c][r] * isq + slope * (float)(j - q)) : NEG_BIG;
                pv[c][r] = vsc;
                mt = fmaxf(mt, vsc);
            }
        mt = fmaxf(mt, __shfl_xor(mt, 16));
        mt = fmaxf(mt, __shfl_xor(mt, 32));
        const float mn = fmaxf(mrow, mt);
        const float alpha = __expf(mrow - mn);
        mrow = mn;
        float s = 0.f;
        #pragma unroll
        for (int c = 0; c < 4; ++c)
            #pragma unroll
            for (int r = 0; r < 4; ++r) {
                const float pe = __expf(pv[c][r] - mn);
                pv[c][r] = pe;
                s += pe;
            }
        s += __shfl_xor(s, 16);
        s += __shfl_xor(s, 32);
        lsum = lsum * alpha + s;

        // redistribute alpha to PV accumulator rows (q = rowg + r)
        float ar[4];
        #pragma unroll
        for (int r = 0; r < 4; ++r) ar[r] = __shfl(alpha, rowg + r);
        #pragma unroll
        for (int f = 0; f < 8; ++f)
            #pragma unroll
            for (int r = 0; r < 4; ++r)
                oacc[f][r] *= ar[r];

        // P pack (cvt_pk) -> per-wave LDS, b64 writes
        #pragma unroll
        for (int c = 0; c < 4; ++c) {
            uint2 pw;
            pw.x = cvtpk(pv[c][0], pv[c][1]);
            pw.y = cvtpk(pv[c][2], pv[c][3]);
            *reinterpret_cast<uint2*>(&Psl[w][lrow][c * 16 + rowg]) = pw;
        }
        asm volatile("s_waitcnt lgkmcnt(0)" ::: "memory");

        #pragma unroll
        for (int kk2 = 0; kk2 < 2; ++kk2) {
            bf16x8 pf = *reinterpret_cast<const bf16x8*>(&Psl[w][lrow][kk2 * 32 + lko]);
            #pragma unroll
            for (int nb = 0; nb < 8; ++nb) {
                bf16x8 vf = *reinterpret_cast<const bf16x8*>(&Vt[nb * 16 + lrow][kk2 * 32 + lko]);
                oacc[nb] = __builtin_amdgcn_mfma_f32_16x16x32_bf16(pf, vf, oacc[nb], 0, 0, 0);
            }
        }

        __syncthreads();             // all waves done reading Ksl/Vt
        if (pre) { wrK(); wrV(); }
        __syncthreads();             // next tile visible
    }

    // epilogue
    float lr[4];
    #pragma unroll
    for (int r = 0; r < 4; ++r) lr[r] = __shfl(lsum, rowg + r);
    #pragma unroll
    for (int nb = 0; nb < 8; ++nb)
        #pragma unroll
        for (int r = 0; r < 4; ++r) {
            const int row = q0 + rowg + r;
            const int col = h * 128 + nb * 16 + lrow;
            const float vo = oacc[nb][r] / lr[r];
            AO[(size_t)(b * 2048 + row) * 2048 + col] = f2b(vo);
        }
}

extern "C" void kernel_launch(void* const* d_in, const int* in_sizes, int n_in,
                              void* d_out, int out_size, void* d_ws, size_t ws_size,
                              hipStream_t stream)
{
    const float* x   = (const float*)d_in[0];  // (2,2048,2048)
    const float* Wq  = (const float*)d_in[1];  // (2048,2048)
    const float* Wkv = (const float*)d_in[2];  // (2048,1024)
    const float* Wo  = (const float*)d_in[3];  // (2048,2048)
    const float* bo  = (const float*)d_in[4];  // (2048,)

    char* ws = (char*)d_ws;
    unsigned short* xb  = (unsigned short*)(ws + (size_t)0);          // 16MB (later AO)
    unsigned short* Wt  = (unsigned short*)(ws + ((size_t)16 << 20)); // 8MB
    unsigned short* Qb  = (unsigned short*)(ws + ((size_t)24 << 20)); // 16MB
    unsigned short* KVb = (unsigned short*)(ws + ((size_t)40 << 20)); // 8MB
    // total 48MB

    // x -> bf16
    k_convert<<<8192, 256, 0, stream>>>(x, xb, (2 * 2048 * 2048) / 4);

    // Q = x @ Wq           (4096 x 2048 x 2048)
    k_transpose<<<dim3(32, 32), 256, 0, stream>>>(Wq, Wt, 2048, 2048);
    k_gemm<<<dim3(16, 32), 256, 0, stream>>>(xb, Wt, Qb, nullptr, 4096, 2048, 2048, 0);
    // KV = x @ Wkv         (4096 x 1024 x 2048)
    k_transpose<<<dim3(16, 32), 256, 0, stream>>>(Wkv, Wt, 2048, 1024);
    k_gemm<<<dim3(8, 32), 256, 0, stream>>>(xb, Wt, KVb, nullptr, 4096, 1024, 2048, 0);
    // attention -> AO (reuses x buffer)
    k_attn<<<1024, 256, 0, stream>>>(Qb, KVb, xb);

    // out = AO @ Wo + bo   (4096 x 2048 x 2048), f32 out
    k_transpose<<<dim3(32, 32), 256, 0, stream>>>(Wo, Wt, 2048, 2048);
    k_gemm<<<dim3(16, 32), 256, 0, stream>>>(xb, Wt, d_out, bo, 4096, 2048, 2048, 1);
}

// Round 7
// 272.466 us; speedup vs baseline: 2.6044x; 1.1199x over previous
//
#include <hip/hip_runtime.h>

typedef __attribute__((ext_vector_type(8))) __bf16 bf16x8;
typedef __attribute__((ext_vector_type(4))) float f32x4;

#define NEG_BIG (-1e30f)

__device__ __forceinline__ unsigned short f2b(float f) {
    unsigned int u = __float_as_uint(f);
    u += 0x7FFFu + ((u >> 16) & 1u);
    return (unsigned short)(u >> 16);
}
__device__ __forceinline__ float b2f(unsigned short h) {
    return __uint_as_float(((unsigned int)h) << 16);
}
__device__ __forceinline__ unsigned cvtpk(float lo, float hi) {
    unsigned r;
    asm("v_cvt_pk_bf16_f32 %0, %1, %2" : "=v"(r) : "v"(lo), "v"(hi));
    return r;
}

typedef const __attribute__((address_space(1))) unsigned int* gas_ptr;
typedef __attribute__((address_space(3))) unsigned int* las_ptr;
__device__ __forceinline__ void gload16(const void* g, void* l) {
    __builtin_amdgcn_global_load_lds((gas_ptr)g, (las_ptr)l, 16, 0, 0);
}

// ---------------- elementwise f32 -> bf16 (rn) ----------------
__global__ __launch_bounds__(256) void k_convert(
    const float* __restrict__ x, unsigned short* __restrict__ xb, int n4)
{
    int i = blockIdx.x * 256 + threadIdx.x;
    if (i >= n4) return;
    float4 v = reinterpret_cast<const float4*>(x)[i];
    ushort4 h;
    h.x = f2b(v.x); h.y = f2b(v.y); h.z = f2b(v.z); h.w = f2b(v.w);
    reinterpret_cast<ushort4*>(xb)[i] = h;
}

// ------------- W (K x N, f32) -> Wt (N x K) bf16 -------------
__global__ __launch_bounds__(256) void k_transpose(
    const float* __restrict__ W, unsigned short* __restrict__ Th, int K, int N)
{
    __shared__ float tile[64][65];
    const int n0 = blockIdx.x * 64, k0 = blockIdx.y * 64;
    const int c = threadIdx.x & 63, r0 = threadIdx.x >> 6;
    for (int rr = r0; rr < 64; rr += 4)
        tile[rr][c] = W[(size_t)(k0 + rr) * N + n0 + c];
    __syncthreads();
    for (int rr = r0; rr < 64; rr += 4)
        Th[(size_t)(n0 + rr) * K + k0 + c] = f2b(tile[c][rr]);
}

// ------------- plain bf16 GEMM: C = A * B^T(stored [N][K]) -------------
// Split epilogue: cols < N1 -> CoutA (row stride NA), cols >= N1 -> CoutB
// (row stride NB, col - N1). 128x128 tile, BK=32, 4 waves.
__global__ __launch_bounds__(256) void k_gemm(
    const unsigned short* __restrict__ A, const unsigned short* __restrict__ B,
    void* __restrict__ CoutA, int NA, void* __restrict__ CoutB, int NB, int N1,
    const float* __restrict__ bias, int M, int K, int outF32)
{
    __shared__ __align__(16) unsigned short As[128][32];
    __shared__ __align__(16) unsigned short Bs[128][32];

    const int tid  = threadIdx.x;
    const int lane = tid & 63, wid = tid >> 6;
    const int wr = wid >> 1, wc = wid & 1;
    const int lrow = lane & 15, lko = (lane >> 4) << 3;
    const int trow = tid >> 2, tk = (tid & 3) << 3;
    const int bm = blockIdx.y, bn = blockIdx.x;
    const int wbyte = wid * 1024;   // lane-linear: thread t -> byte 16*t

    f32x4 acc[4][4] = {};

    const size_t aoff = (size_t)(bm * 128 + trow) * K + tk;
    const size_t boff = (size_t)(bn * 128 + trow) * K + tk;
    const size_t half = (size_t)64 * K;

    for (int k0 = 0; k0 < K; k0 += 32) {
        gload16(&A[aoff + k0],        (char*)&As[0][0] + wbyte);
        gload16(&A[aoff + half + k0], (char*)&As[0][0] + 4096 + wbyte);
        gload16(&B[boff + k0],        (char*)&Bs[0][0] + wbyte);
        gload16(&B[boff + half + k0], (char*)&Bs[0][0] + 4096 + wbyte);
        __syncthreads();

        bf16x8 af[4], bf[4];
        #pragma unroll
        for (int m = 0; m < 4; ++m)
            af[m] = *reinterpret_cast<const bf16x8*>(&As[wr * 64 + m * 16 + lrow][lko]);
        #pragma unroll
        for (int n = 0; n < 4; ++n)
            bf[n] = *reinterpret_cast<const bf16x8*>(&Bs[wc * 64 + n * 16 + lrow][lko]);
        #pragma unroll
        for (int m = 0; m < 4; ++m)
            #pragma unroll
            for (int n = 0; n < 4; ++n)
                acc[m][n] = __builtin_amdgcn_mfma_f32_16x16x32_bf16(af[m], bf[n], acc[m][n], 0, 0, 0);
        __syncthreads();
    }

    const int rbase = bm * 128 + wr * 64 + ((lane >> 4) << 2);
    const int cbase = bn * 128 + wc * 64 + lrow;
    #pragma unroll
    for (int m = 0; m < 4; ++m)
        #pragma unroll
        for (int n = 0; n < 4; ++n) {
            const int col = cbase + n * 16;
            const float bv = bias ? bias[col] : 0.0f;
            const bool inA = (col < N1);
            const int ccol = inA ? col : (col - N1);
            const int cstr = inA ? NA : NB;
            void* base = inA ? CoutA : CoutB;
            #pragma unroll
            for (int r = 0; r < 4; ++r) {
                const size_t idx = (size_t)(rbase + m * 16 + r) * cstr + ccol;
                const float v = acc[m][n][r] + bv;
                if (outF32) ((float*)base)[idx] = v;
                else        ((unsigned short*)base)[idx] = f2b(v);
            }
        }
}

// ------------- fused causal GQA attention with ALiBi -------------
// (verified round-5 version) block = (b, g, qt), work-descending order.
// 4 waves = 4 q-heads sharing kv head g. KVBLK=64, single-buffered K
// (XOR-swizzled, reg-staged early-issue/late-write) and V (gather-transpose,
// same). Swapped QK^T: lane owns one q-row -> in-lane softmax.
__global__ __launch_bounds__(256, 3) void k_attn(
    const unsigned short* __restrict__ Qb,   // (B*T) x 2048 bf16
    const unsigned short* __restrict__ KVb,  // (B*T) x 1024 bf16 (k | v)
    unsigned short* __restrict__ AO)         // (B*T) x 2048 bf16
{
    __shared__ __align__(16) unsigned short Ksl[64][128]; // [key][dim ^ ((key&7)<<3)]
    __shared__ __align__(16) unsigned short Vt[128][72];  // [dim][key], padded
    __shared__ __align__(16) unsigned short Psl[4][16][72];

    const int blk = blockIdx.x;
    const int ord = blk >> 3;          // 0..127, descending work
    const int sub = blk & 7;
    const int b   = sub >> 2;
    const int g   = sub & 3;
    const int qt  = 127 - ord;
    const int q0  = qt * 16;

    const int tid = threadIdx.x;
    const int lane = tid & 63;
    const int w = tid >> 6;          // rep index r
    const int h = w * 4 + g;         // query head
    const float slope = exp2f(-0.5f * (float)(h + 1));
    const float isq = 0.088388347648318447f; // 1/sqrt(128)
    const int lrow = lane & 15;
    const int lko  = (lane >> 4) << 3;
    const int rowg = (lane >> 4) << 2;
    const int skey = tid >> 4;                 // 0..15
    const int sd0  = (tid & 15) << 3;          // 0..120
    const int vdim = tid & 127;                // V gather: dim
    const int vkg  = tid >> 7;                 // V gather: key-group parity

    uint4 kreg[4];                             // in-flight K tile (regs)
    unsigned short vv[4][8];                   // in-flight V tile (regs)

    auto ldK = [&](int kb) {
        const int j0 = kb << 6;
        #pragma unroll
        for (int pp = 0; pp < 4; ++pp) {
            const int key = skey + pp * 16;
            kreg[pp] = *reinterpret_cast<const uint4*>(
                &KVb[(size_t)(b * 2048 + j0 + key) * 1024 + g * 128 + sd0]);
        }
    };
    auto wrK = [&]() {
        #pragma unroll
        for (int pp = 0; pp < 4; ++pp) {
            const int key = skey + pp * 16;
            *reinterpret_cast<uint4*>(&Ksl[key][sd0 ^ ((key & 7) << 3)]) = kreg[pp];
        }
    };
    auto ldV = [&](int kb) {
        const int j0 = kb << 6;
        #pragma unroll
        for (int gi = 0; gi < 4; ++gi) {
            const int kgi = gi * 2 + vkg;
            const size_t base = (size_t)(b * 2048 + j0 + kgi * 8) * 1024 + 512 + g * 128 + vdim;
            #pragma unroll
            for (int j = 0; j < 8; ++j)
                vv[gi][j] = KVb[base + (size_t)j * 1024];
        }
    };
    auto wrV = [&]() {
        #pragma unroll
        for (int gi = 0; gi < 4; ++gi) {
            const int kgi = gi * 2 + vkg;
            *reinterpret_cast<uint4*>(&Vt[vdim][kgi * 8]) =
                *reinterpret_cast<const uint4*>(&vv[gi][0]);
        }
    };

    bf16x8 qf[4];
    {
        const size_t qoff = (size_t)(b * 2048 + q0 + lrow) * 2048 + h * 128 + lko;
        #pragma unroll
        for (int kk = 0; kk < 4; ++kk)
            qf[kk] = *reinterpret_cast<const bf16x8*>(&Qb[qoff + kk * 32]);
    }

    f32x4 oacc[8] = {};
    float mrow = NEG_BIG, lsum = 0.f;
    const int nkb = (q0 + 16 + 63) >> 6;
    const int q = q0 + lrow;                   // this lane's q-row

    // prologue: stage tile 0
    ldK(0); ldV(0);
    wrK(); wrV();
    __syncthreads();

    for (int kb = 0; kb < nkb; ++kb) {
        const int j0 = kb << 6;
        const bool pre = (kb + 1 < nkb);
        if (pre) { ldK(kb + 1); ldV(kb + 1); }

        // S^T = K Q^T : lane owns q-row q, 16 keys in regs
        f32x4 sa[4] = {};
        #pragma unroll
        for (int c = 0; c < 4; ++c) {
            const int krow = c * 16 + lrow;
            #pragma unroll
            for (int kk = 0; kk < 4; ++kk) {
                bf16x8 kf = *reinterpret_cast<const bf16x8*>(
                    &Ksl[krow][(kk * 32 + lko) ^ ((krow & 7) << 3)]);
                sa[c] = __builtin_amdgcn_mfma_f32_16x16x32_bf16(kf, qf[kk], sa[c], 0, 0, 0);
            }
        }

        // in-lane softmax over 16 values (one q-row per lane)
        float pv[4][4];
        float mt = NEG_BIG;
        #pragma unroll
        for (int c = 0; c < 4; ++c)
            #pragma unroll
            for (int r = 0; r < 4; ++r) {
                const int j = j0 + c * 16 + rowg + r;
                const float vsc = (j <= q) ? (sa[c][r] * isq + slope * (float)(j - q)) : NEG_BIG;
                pv[c][r] = vsc;
                mt = fmaxf(mt, vsc);
            }
        mt = fmaxf(mt, __shfl_xor(mt, 16));
        mt = fmaxf(mt, __shfl_xor(mt, 32));
        const float mn = fmaxf(mrow, mt);
        const float alpha = __expf(mrow - mn);
        mrow = mn;
        float s = 0.f;
        #pragma unroll
        for (int c = 0; c < 4; ++c)
            #pragma unroll
            for (int r = 0; r < 4; ++r) {
                const float pe = __expf(pv[c][r] - mn);
                pv[c][r] = pe;
                s += pe;
            }
        s += __shfl_xor(s, 16);
        s += __shfl_xor(s, 32);
        lsum = lsum * alpha + s;

        // redistribute alpha to PV accumulator rows (q = rowg + r)
        float ar[4];
        #pragma unroll
        for (int r = 0; r < 4; ++r) ar[r] = __shfl(alpha, rowg + r);
        #pragma unroll
        for (int f = 0; f < 8; ++f)
            #pragma unroll
            for (int r = 0; r < 4; ++r)
                oacc[f][r] *= ar[r];

        // P pack (cvt_pk) -> per-wave LDS, b64 writes
        #pragma unroll
        for (int c = 0; c < 4; ++c) {
            uint2 pw;
            pw.x = cvtpk(pv[c][0], pv[c][1]);
            pw.y = cvtpk(pv[c][2], pv[c][3]);
            *reinterpret_cast<uint2*>(&Psl[w][lrow][c * 16 + rowg]) = pw;
        }
        asm volatile("s_waitcnt lgkmcnt(0)" ::: "memory");

        #pragma unroll
        for (int kk2 = 0; kk2 < 2; ++kk2) {
            bf16x8 pf = *reinterpret_cast<const bf16x8*>(&Psl[w][lrow][kk2 * 32 + lko]);
            #pragma unroll
            for (int nb = 0; nb < 8; ++nb) {
                bf16x8 vf = *reinterpret_cast<const bf16x8*>(&Vt[nb * 16 + lrow][kk2 * 32 + lko]);
                oacc[nb] = __builtin_amdgcn_mfma_f32_16x16x32_bf16(pf, vf, oacc[nb], 0, 0, 0);
            }
        }

        __syncthreads();             // all waves done reading Ksl/Vt
        if (pre) { wrK(); wrV(); }
        __syncthreads();             // next tile visible
    }

    // epilogue
    float lr[4];
    #pragma unroll
    for (int r = 0; r < 4; ++r) lr[r] = __shfl(lsum, rowg + r);
    #pragma unroll
    for (int nb = 0; nb < 8; ++nb)
        #pragma unroll
        for (int r = 0; r < 4; ++r) {
            const int row = q0 + rowg + r;
            const int col = h * 128 + nb * 16 + lrow;
            const float vo = oacc[nb][r] / lr[r];
            AO[(size_t)(b * 2048 + row) * 2048 + col] = f2b(vo);
        }
}

extern "C" void kernel_launch(void* const* d_in, const int* in_sizes, int n_in,
                              void* d_out, int out_size, void* d_ws, size_t ws_size,
                              hipStream_t stream)
{
    const float* x   = (const float*)d_in[0];  // (2,2048,2048)
    const float* Wq  = (const float*)d_in[1];  // (2048,2048)
    const float* Wkv = (const float*)d_in[2];  // (2048,1024)
    const float* Wo  = (const float*)d_in[3];  // (2048,2048)
    const float* bo  = (const float*)d_in[4];  // (2048,)

    char* ws = (char*)d_ws;
    unsigned short* xb  = (unsigned short*)(ws + (size_t)0);          // 16MB (later AO)
    unsigned short* Wt  = (unsigned short*)(ws + ((size_t)16 << 20)); // 12MB (3072x2048)
    unsigned short* Qb  = (unsigned short*)(ws + ((size_t)28 << 20)); // 16MB
    unsigned short* KVb = (unsigned short*)(ws + ((size_t)44 << 20)); // 8MB
    // total 52MB

    // x -> bf16
    k_convert<<<8192, 256, 0, stream>>>(x, xb, (2 * 2048 * 2048) / 4);

    // Wt rows 0..2047 = Wq^T, rows 2048..3071 = Wkv^T
    k_transpose<<<dim3(32, 32), 256, 0, stream>>>(Wq, Wt, 2048, 2048);
    k_transpose<<<dim3(16, 32), 256, 0, stream>>>(Wkv, Wt + (size_t)2048 * 2048, 2048, 1024);

    // fused QKV = x @ [Wq | Wkv]  (4096 x 3072 x 2048), split outputs
    k_gemm<<<dim3(24, 32), 256, 0, stream>>>(xb, Wt, Qb, 2048, KVb, 1024, 2048,
                                             nullptr, 4096, 2048, 0);

    // attention -> AO (reuses x buffer)
    k_attn<<<1024, 256, 0, stream>>>(Qb, KVb, xb);

    // out = AO @ Wo + bo   (4096 x 2048 x 2048), f32 out
    k_transpose<<<dim3(32, 32), 256, 0, stream>>>(Wo, Wt, 2048, 2048);
    k_gemm<<<dim3(16, 32), 256, 0, stream>>>(xb, Wt, d_out, 2048, nullptr, 2048, 2048,
                                             bo, 4096, 2048, 1);
}